// Round 10
// baseline (651.593 us; speedup 1.0000x reference)
//
#include <hip/hip_runtime.h>
#include <hip/hip_bf16.h>

#define T_ 512

using sh8 = __attribute__((ext_vector_type(8))) short;  // 8 bf16
using fx4 = __attribute__((ext_vector_type(4))) float;  // MFMA acc

__device__ __forceinline__ short bf16r(float x) {
  union { float f; unsigned u; } v; v.f = x;
  unsigned u = v.u;
  u += 0x7fffu + ((u >> 16) & 1u);   // RNE
  return (short)(u >> 16);
}
__device__ __forceinline__ float b2f(short s) {
  union { float f; unsigned u; } v; v.u = ((unsigned)(unsigned short)s) << 16;
  return v.f;
}
__device__ __forceinline__ fx4 mfma_bf16(sh8 a, sh8 b, fx4 c) {
  return __builtin_amdgcn_mfma_f32_16x16x32_bf16(a, b, c, 0, 0, 0);
}

// ---------------------------------------------------------------------------
// k_prep: weights f32->bf16; permuted gamma/beta tables; per-head constants
//   HC[h][4] = {Ggg=Σgq·gk, Gqb=Σgq·bk, Gkb=Σgk·bq, Bbb=Σbq·bk} over d'=1024.
__global__ __launch_bounds__(256) void k_prep(
    const float* __restrict__ qw, const float* __restrict__ pw,
    const float* __restrict__ gamma, const float* __restrict__ beta,
    short* __restrict__ qwb, short* __restrict__ pwb,
    float* __restrict__ gq, float* __restrict__ bq,
    float* __restrict__ gv, float* __restrict__ bv,
    float* __restrict__ HC)
{
  __shared__ float cred[4][4];
  if (blockIdx.x >= 192) {            // per-head constant blocks
    const int h = blockIdx.x - 192;
    float c0 = 0.f, c1 = 0.f, c2 = 0.f, c3 = 0.f;
    #pragma unroll
    for (int e = 0; e < 4; ++e) {
      const int dp = threadIdx.x * 4 + e;
      const int cl = dp & 15, fq = dp >> 4;
      const float gqv = gamma[(h * 48 + cl) * 64 + fq];
      const float gkv = gamma[(h * 48 + 16 + cl) * 64 + fq];
      const float bqv = beta[(h * 48 + cl) * 64 + fq];
      const float bkv = beta[(h * 48 + 16 + cl) * 64 + fq];
      c0 += gqv * gkv; c1 += gqv * bkv; c2 += gkv * bqv; c3 += bqv * bkv;
    }
    #pragma unroll
    for (int off = 32; off > 0; off >>= 1) {
      c0 += __shfl_down(c0, off); c1 += __shfl_down(c1, off);
      c2 += __shfl_down(c2, off); c3 += __shfl_down(c3, off);
    }
    if ((threadIdx.x & 63) == 0) {
      cred[threadIdx.x >> 6][0] = c0; cred[threadIdx.x >> 6][1] = c1;
      cred[threadIdx.x >> 6][2] = c2; cred[threadIdx.x >> 6][3] = c3;
    }
    __syncthreads();
    if (threadIdx.x < 4) {
      float s = 0.f;
      for (int k2 = 0; k2 < 4; ++k2) s += cred[k2][threadIdx.x];
      HC[h * 4 + threadIdx.x] = s;
    }
    return;
  }
  const int i = blockIdx.x * 256 + threadIdx.x;
  if (i < 49152) qwb[i] = bf16r(qw[i]);
  if (i < 16384) pwb[i] = bf16r(pw[i]);
  if (i < 16384) {
    const int sh = i >> 10, dp = i & 1023;
    const int sect = sh >> 3, h = sh & 7;
    const int gi = (h * 48 + sect * 16 + (dp & 15)) * 64 + (dp >> 4);
    gq[i] = gamma[gi]; bq[i] = beta[gi];
  }
  if (i < 8192) {
    const int h = i >> 10, d = i & 1023;
    const int gi = (h * 48 + 32 + (d >> 6)) * 64 + (d & 63);
    gv[i] = gamma[gi]; bv[i] = beta[gi];
  }
}

// ---------------------------------------------------------------------------
// k_xt: x f32 [b][c][f][t] -> Xb bf16 [(b*64+f)*16 + c/8][t][c%8]
__global__ __launch_bounds__(256) void k_xt(const float* __restrict__ x,
                                            short* __restrict__ Xb)
{
  const int bid = blockIdx.x;
  const int b = bid >> 8, f = (bid >> 2) & 63, tt = bid & 3;
  const int tid = threadIdx.x;

  __shared__ short Xraw[128 * 128];   // [c][tl], 256B pitch, swz ((c&7)<<4)

  {
    const int tq = (tid & 31) * 4, c0 = tid >> 5;
    const float* xp = x + (((size_t)(b * 128 + c0) * 64 + f) * 512) + tt * 128 + tq;
    #pragma unroll
    for (int p = 0; p < 16; ++p) {
      const int c = c0 + p * 8;
      const float4 fv = *(const float4*)xp;
      xp += 262144;
      short4 o;
      o.x = bf16r(fv.x); o.y = bf16r(fv.y); o.z = bf16r(fv.z); o.w = bf16r(fv.w);
      *(short4*)((char*)Xraw + c * 256 + ((2 * tq) ^ ((c & 7) << 4))) = o;
    }
  }
  __syncthreads();

  short* xb = Xb + (size_t)((b * 64 + f) * 16) * 4096;
  #pragma unroll
  for (int it = 0; it < 8; ++it) {
    const int chunk = tid + it * 256;
    const int c8 = chunk >> 7, tl = chunk & 127;
    sh8 o;
    #pragma unroll
    for (int e = 0; e < 8; ++e)
      o[e] = *((const short*)((const char*)Xraw + (c8 * 8 + e) * 256 + ((2 * tl) ^ (e << 4))));
    *(sh8*)(xb + ((size_t)c8 * 512 + tt * 128 + tl) * 8) = o;
  }
}

// ---------------------------------------------------------------------------
// kA: per (b, f, tt): Y[384,128] = W @ X; bias+PReLU; stats (s0,s1 + per-head
//     weighted sums for the LN-decomposition); stores Q~=g∘Q, K~=g∘K
//     [bh][t][d'], V raw [bh][d][t].
__global__ __launch_bounds__(512) void kA_qkv(
    const short* __restrict__ Xb, const short* __restrict__ wb,
    const float* __restrict__ bias, const float* __restrict__ alphap,
    const float* __restrict__ gq, const float* __restrict__ bq,
    short* __restrict__ Qp, short* __restrict__ Kp, short* __restrict__ Vt,
    float* __restrict__ Pstat)
{
  const int bid = blockIdx.x;
  const int b = bid >> 8, f = (bid >> 2) & 63, tt = bid & 3;
  const int tid = threadIdx.x, lane = tid & 63, w = tid >> 6;

  __shared__ float psum[8 * 8 * 16 * 6];   // [w][ni][l16][ch], 24KB

  fx4 acc[3][8];
  #pragma unroll
  for (int mi = 0; mi < 3; ++mi)
    #pragma unroll
    for (int ni = 0; ni < 8; ++ni) acc[mi][ni] = fx4{0.f, 0.f, 0.f, 0.f};

  const short* xb = Xb + (size_t)((b * 64 + f) * 16) * 4096;

  #pragma unroll
  for (int ks = 0; ks < 4; ++ks) {
    sh8 a[3];
    #pragma unroll
    for (int mi = 0; mi < 3; ++mi) {
      const int o = w * 48 + mi * 16 + (lane & 15);
      a[mi] = *(const sh8*)(wb + o * 128 + ks * 32 + (lane >> 4) * 8);
    }
    #pragma unroll
    for (int ni = 0; ni < 8; ++ni) {
      const sh8 bf = *(const sh8*)(xb + ((size_t)(ks * 4 + (lane >> 4)) * 512 +
                                         tt * 128 + ni * 16 + (lane & 15)) * 8);
      #pragma unroll
      for (int mi = 0; mi < 3; ++mi)
        acc[mi][ni] = mfma_bf16(a[mi], bf, acc[mi][ni]);
    }
  }

  // tables for this thread's 4 cl values
  float gqq[4], gqk[4], bqq[4], bqk[4];
  #pragma unroll
  for (int r = 0; r < 4; ++r) {
    const int dp = f * 16 + (lane >> 4) * 4 + r;
    gqq[r] = gq[w * 1024 + dp];
    gqk[r] = gq[(8 + w) * 1024 + dp];
    bqq[r] = bq[w * 1024 + dp];
    bqk[r] = bq[(8 + w) * 1024 + dp];
  }

  const float alpha = alphap[0];
  #pragma unroll
  for (int ni = 0; ni < 8; ++ni) {
    float t0 = 0.f, t1 = 0.f, taq = 0.f, tuq = 0.f, tak = 0.f, tuk = 0.f;
    #pragma unroll
    for (int mi = 0; mi < 3; ++mi)
      #pragma unroll
      for (int r = 0; r < 4; ++r) {
        const int o = w * 48 + mi * 16 + (lane >> 4) * 4 + r;
        float v = acc[mi][ni][r] + bias[o];
        v = (v >= 0.f) ? v : alpha * v;
        acc[mi][ni][r] = v;
        t0 += v; t1 += v * v;
        if (mi == 0) { const float qt = v * gqq[r]; taq += qt * gqk[r]; tuq += qt * bqk[r]; }
        if (mi == 1) { const float kt = v * gqk[r]; tak += kt * gqq[r]; tuk += kt * bqq[r]; }
      }
    t0 += __shfl_down(t0, 32); t1 += __shfl_down(t1, 32);
    taq += __shfl_down(taq, 32); tuq += __shfl_down(tuq, 32);
    tak += __shfl_down(tak, 32); tuk += __shfl_down(tuk, 32);
    t0 += __shfl_down(t0, 16); t1 += __shfl_down(t1, 16);
    taq += __shfl_down(taq, 16); tuq += __shfl_down(tuq, 16);
    tak += __shfl_down(tak, 16); tuk += __shfl_down(tuk, 16);
    if (lane < 16) {
      float* ps = &psum[((w * 8 + ni) * 16 + lane) * 6];
      ps[0] = t0; ps[1] = t1; ps[2] = taq; ps[3] = tuq; ps[4] = tak; ps[5] = tuk;
    }
  }
  __syncthreads();

  if (tid < 256) {   // s0,s1 summed over waves
    const int col = tid & 127, s = tid >> 7;
    const int ni = col >> 4, l = col & 15;
    float a0 = 0.f;
    #pragma unroll
    for (int ww = 0; ww < 8; ++ww) a0 += psum[((ww * 8 + ni) * 16 + l) * 6 + s];
    Pstat[(size_t)s * 131072 + (size_t)b * 32768 + (size_t)f * 512 + tt * 128 + col] = a0;
  }
  #pragma unroll
  for (int p = 0; p < 8; ++p) {   // per-head channels
    const int idx = p * 512 + tid;
    const int col = idx & 127, wc = idx >> 7;
    const int ww = wc >> 2, ch = wc & 3;
    const int ni = col >> 4, l = col & 15;
    Pstat[(size_t)(2 + ww * 4 + ch) * 131072 + (size_t)b * 32768 +
          (size_t)f * 512 + tt * 128 + col] = psum[((ww * 8 + ni) * 16 + l) * 6 + 2 + ch];
  }

  // stores: Q~/K~ [bh][t][d'] packed uint2 (g folded); V raw [d][t]
  const int bh = b * 8 + w;
  #pragma unroll
  for (int mi = 0; mi < 2; ++mi) {
    short* dst = mi ? Kp : Qp;
    #pragma unroll
    for (int ni = 0; ni < 8; ++ni) {
      const int t = tt * 128 + ni * 16 + (lane & 15);
      float v0 = acc[mi][ni][0] * (mi == 0 ? gqq[0] : gqk[0]);
      float v1 = acc[mi][ni][1] * (mi == 0 ? gqq[1] : gqk[1]);
      float v2 = acc[mi][ni][2] * (mi == 0 ? gqq[2] : gqk[2]);
      float v3 = acc[mi][ni][3] * (mi == 0 ? gqq[3] : gqk[3]);
      const unsigned lo = (unsigned)(unsigned short)bf16r(v0) |
                          ((unsigned)(unsigned short)bf16r(v1) << 16);
      const unsigned hi = (unsigned)(unsigned short)bf16r(v2) |
                          ((unsigned)(unsigned short)bf16r(v3) << 16);
      uint2 pk; pk.x = lo; pk.y = hi;
      *(uint2*)(dst + ((size_t)bh * 512 + t) * 1024 + f * 16 + (lane >> 4) * 4) = pk;
    }
  }
  #pragma unroll
  for (int ni = 0; ni < 8; ++ni)
    #pragma unroll
    for (int r = 0; r < 4; ++r) {
      const int cl = (lane >> 4) * 4 + r;
      Vt[((size_t)bh * 1024 + cl * 64 + f) * 512 + tt * 128 + ni * 16 + (lane & 15)] =
          bf16r(acc[2][ni][r]);
    }
}

// ---------------------------------------------------------------------------
// k_stats: per (b,h,t): mu/rs from s0,s1; bundle
//   RowB[b*8+h][t][8] = {rs, rs*mu, rs*aq, rs*uq - rm*Gqb, rs*ak, rs*uk - rm*Gkb, 0, 0}
__global__ __launch_bounds__(256) void k_stats(const float* __restrict__ Pstat,
                                               const float* __restrict__ HC,
                                               float* __restrict__ RowB)
{
  const int idx = blockIdx.x * 256 + threadIdx.x;   // 16384
  const int b = idx >> 12, h = (idx >> 9) & 7, t = idx & 511;
  const float* P0 = Pstat + (size_t)b * 32768 + t;
  float s0 = 0.f, s1 = 0.f, aq = 0.f, uq = 0.f, ak = 0.f, uk = 0.f;
  for (int fq = 0; fq < 64; ++fq) {
    const size_t o = (size_t)fq * 512;
    s0 += P0[o];
    s1 += P0[(size_t)131072 + o];
    aq += P0[(size_t)(2 + h * 4 + 0) * 131072 + o];
    uq += P0[(size_t)(2 + h * 4 + 1) * 131072 + o];
    ak += P0[(size_t)(2 + h * 4 + 2) * 131072 + o];
    uk += P0[(size_t)(2 + h * 4 + 3) * 131072 + o];
  }
  const float mu = s0 * (1.f / 24576.f);
  const float var = s1 * (1.f / 24576.f) - mu * mu;
  const float rs = rsqrtf(var + 1e-5f);
  const float rm = rs * mu;
  float* o8 = RowB + ((size_t)(b * 8 + h) * 512 + t) * 8;
  o8[0] = rs;
  o8[1] = rm;
  o8[2] = rs * aq;
  o8[3] = rs * uq - rm * HC[h * 4 + 1];
  o8[4] = rs * ak;
  o8[5] = rs * uk - rm * HC[h * 4 + 2];
  o8[6] = 0.f; o8[7] = 0.f;
}

// ---------------------------------------------------------------------------
// k_flash: fused QK^T (on Q~,K~ with affine LN-correction) + causal online
//   softmax + P'V (raw V, LN folded into epilogue) -> Cs scrambled layout.
//   Block = (bh, q-tile 64, d-half 512). 256 thr, 4 waves; wave w owns q rows
//   [w*16, w*16+16) x ALL 128 k of each k-tile -> softmax state never crosses
//   waves.
__global__ __launch_bounds__(256, 2) void k_flash(
    const short* __restrict__ Qp, const short* __restrict__ Kp,
    const short* __restrict__ Vt, const float* __restrict__ RowB,
    const float* __restrict__ gvt, const float* __restrict__ bvt,
    const float* __restrict__ HC, short* __restrict__ Cs)
{
  const int bid = blockIdx.x;
  const int qx = bid >> 6;
  const int qi = (qx < 4) ? qx : (11 - qx);      // pair heavy+light across dispatch
  const int dh = (bid >> 5) & 1, bh = bid & 31;
  const int b = bh >> 3, h = bh & 7;
  const int tid = threadIdx.x, lane = tid & 63, w = tid >> 6;

  __shared__ __align__(16) char smem[65536];
  // layout: Qc/Pl @0 (16KB), Kc @16384 (32KB), kb @49152 (2KB), qb @51200 (1KB)
  // epilogue: ctile [512][64] bf16 @0 (64KB) — kb/qb dead by then
  float4* kb = (float4*)(smem + 49152);
  float4* qb = (float4*)(smem + 51200);

  const float Ggg = HC[h * 4 + 0], Bbb = HC[h * 4 + 3];

  if (tid < 64)
    qb[tid] = *(const float4*)(RowB + ((size_t)(b * 8 + h) * 512 + qi * 64 + tid) * 8);

  const short* Qg = Qp + ((size_t)bh * 512 + qi * 64) * 1024;
  const short* Kg = Kp + (size_t)bh * 512 * 1024;
  const short* Vg = Vt + (size_t)bh * 1024 * 512;

  fx4 oacc[32];   // 16 q rows x 512 d (dh half)
  #pragma unroll
  for (int nd = 0; nd < 32; ++nd) oacc[nd] = fx4{0.f, 0.f, 0.f, 0.f};
  float mq[4], lq[4], saq[4];
  #pragma unroll
  for (int i = 0; i < 4; ++i) { mq[i] = -1e30f; lq[i] = 0.f; saq[i] = 0.f; }

  const int KT = (qi >> 1) + 1;
  for (int kt = 0; kt < KT; ++kt) {
    __syncthreads();
    if (tid < 128) {
      const float* rb = RowB + ((size_t)(b * 8 + h) * 512 + kt * 128 + tid) * 8;
      const float4 lo = *(const float4*)rb;
      const float4 hi = *(const float4*)(rb + 4);
      kb[tid] = float4{lo.x, lo.y, hi.x, hi.y};   // {rs_k, rm_k, Ak, Uk}
    }

    // ---- QK on Q~,K~: wave w -> q rows [w*16, w*16+16), all 128 k ----
    fx4 sacc[8];
    #pragma unroll
    for (int ni = 0; ni < 8; ++ni) sacc[ni] = fx4{0.f, 0.f, 0.f, 0.f};

    for (int ks = 0; ks < 8; ++ks) {
      __syncthreads();
      #pragma unroll
      for (int p = 0; p < 4; ++p) {       // Qc: 1024 chunks
        const int idx = tid + p * 256;
        const int row = idx >> 4, c = idx & 15;
        const sh8 v = *(const sh8*)(Qg + (size_t)row * 1024 + ks * 128 + c * 8);
        *(sh8*)(smem + row * 256 + ((c * 16) ^ ((row & 7) << 4))) = v;
      }
      #pragma unroll
      for (int p = 0; p < 8; ++p) {       // Kc: 2048 chunks
        const int idx = tid + p * 256;
        const int row = idx >> 4, c = idx & 15;
        const sh8 v = *(const sh8*)(Kg + (size_t)(kt * 128 + row) * 1024 + ks * 128 + c * 8);
        *(sh8*)(smem + 16384 + row * 256 + ((c * 16) ^ ((row & 7) << 4))) = v;
      }
      __syncthreads();
      #pragma unroll
      for (int kk = 0; kk < 4; ++kk) {
        const int arow = w * 16 + (lane & 15);
        const sh8 a = *(const sh8*)(smem + arow * 256 +
                      (((kk * 32 + (lane >> 4) * 8) * 2) ^ ((arow & 7) << 4)));
        #pragma unroll
        for (int ni = 0; ni < 8; ++ni) {
          const int brow = ni * 16 + (lane & 15);
          const sh8 bbf = *(const sh8*)(smem + 16384 + brow * 256 +
                          (((kk * 32 + (lane >> 4) * 8) * 2) ^ ((brow & 7) << 4)));
          sacc[ni] = mfma_bf16(a, bbf, sacc[ni]);
        }
      }
    }
    __syncthreads();   // all QK reads of Qc done before Pl (same region) writes

    // ---- affine correction + mask + online softmax (rows wholly in-wave) ----
    float pm[4];
    #pragma unroll
    for (int r = 0; r < 4; ++r) pm[r] = -3e30f;

    #pragma unroll
    for (int ni = 0; ni < 8; ++ni) {
      const int kl = ni * 16 + (lane & 15);
      const float4 kv = kb[kl];
      #pragma unroll
      for (int r = 0; r < 4; ++r) {
        const int ql = w * 16 + (lane >> 4) * 4 + r;
        const float4 qv = qb[ql];
        float s = sacc[ni][r];
        s = qv.x * kv.x * s - qv.z * kv.y - qv.y * kv.z + (qv.y * kv.y) * Ggg
            + qv.w + kv.w + Bbb;
        s *= 0.03125f;
        if (kt * 128 + kl > qi * 64 + ql) s = -3e30f;
        sacc[ni][r] = s;
        pm[r] = fmaxf(pm[r], s);
      }
    }
    #pragma unroll
    for (int r = 0; r < 4; ++r) {
      float v = pm[r];
      v = fmaxf(v, __shfl_xor(v, 1)); v = fmaxf(v, __shfl_xor(v, 2));
      v = fmaxf(v, __shfl_xor(v, 4)); v = fmaxf(v, __shfl_xor(v, 8));
      const float mn = fmaxf(mq[r], v);
      const float fsc = __expf(mq[r] - mn);
      mq[r] = mn;
      lq[r] *= fsc; saq[r] *= fsc;
      #pragma unroll
      for (int nd = 0; nd < 32; ++nd) oacc[nd][r] *= fsc;
    }
    #pragma unroll
    for (int ni = 0; ni < 8; ++ni) {
      const int kl = ni * 16 + (lane & 15);
      const float4 kv = kb[kl];
      #pragma unroll
      for (int r = 0; r < 4; ++r) {
        const int ql = w * 16 + (lane >> 4) * 4 + r;
        const float p = __expf(sacc[ni][r] - mq[r]);
        lq[r] += p; saq[r] += p * kv.y;
        *((short*)(smem + ql * 256 + ((kl * 2) ^ ((ql & 7) << 4)))) = bf16r(p * kv.x);
      }
    }
    __syncthreads();   // Pl visible (each wave wrote only its own 16 rows)

    // ---- PV: A = P' rows of this wave, B = raw V direct from global ----
    #pragma unroll
    for (int kk = 0; kk < 4; ++kk) {
      const int arow = w * 16 + (lane & 15);
      const sh8 a2 = *(const sh8*)(smem + arow * 256 +
                     (((kk * 32 + (lane >> 4) * 8) * 2) ^ ((arow & 7) << 4)));
      #pragma unroll
      for (int nd = 0; nd < 32; ++nd) {
        const sh8 vb = *(const sh8*)(Vg +
            ((size_t)(dh * 512 + nd * 16 + (lane & 15))) * 512 +
            kt * 128 + kk * 32 + (lane >> 4) * 8);
        oacc[nd] = mfma_bf16(a2, vb, oacc[nd]);
      }
    }
  }

  // ---- epilogue: finalize rows, LN-correct with gv/bv, -> ctile -> Cs ----
  #pragma unroll
  for (int r = 0; r < 4; ++r) {
    float L = lq[r], S = saq[r];
    #pragma unroll
    for (int off = 1; off < 16; off <<= 1) {
      L += __shfl_xor(L, off); S += __shfl_xor(S, off);
    }
    lq[r] = 1.0f / L; saq[r] = S;
  }
  __syncthreads();   // before ctile overwrites everything

  #pragma unroll
  for (int nd = 0; nd < 32; ++nd) {
    const int dl = nd * 16 + (lane & 15);
    const float gvv = gvt[h * 1024 + dh * 512 + dl];
    const float bvv = bvt[h * 1024 + dh * 512 + dl];
    const int swz = (dl & 7) << 4;
    #pragma unroll
    for (int r = 0; r < 4; ++r) {
      const int ql = w * 16 + (lane >> 4) * 4 + r;
      const float o = gvv * (oacc[nd][r] - saq[r]) * lq[r] + bvv;
      *((short*)(smem + dl * 128 + ((ql * 2) ^ swz))) = bf16r(o);
    }
  }
  __syncthreads();

  #pragma unroll
  for (int rr = 0; rr < 2; ++rr) {
    const int dl = rr * 256 + tid;
    const int C = h * 16 + dh * 8 + (dl >> 6);
    const int t2 = (dl & 63) * 8 + qi;
    short* dst = Cs + (((size_t)b * 128 + C) * 512 + t2) * 64;
    const int swz = (dl & 7) << 4;
    #pragma unroll
    for (int j = 0; j < 8; ++j) {
      const sh8 vv = *(const sh8*)(smem + dl * 128 + ((j * 16) ^ swz));
      *(sh8*)(dst + j * 8) = vv;
    }
  }
}

// ---------------------------------------------------------------------------
// k_proj: per (b,t2): Y[128,64] = Wp @ C; bias+PReLU+LN; -> Otmp bf16 [b][o][t2][f2]
__global__ __launch_bounds__(512) void k_proj(
    const short* __restrict__ Cs, const short* __restrict__ wb,
    const float* __restrict__ bias, const float* __restrict__ alphap,
    const float* __restrict__ gamma, const float* __restrict__ beta,
    short* __restrict__ Otmpb)
{
  const int bid = blockIdx.x;
  const int b = bid >> 9, t2 = bid & 511;
  const int tid = threadIdx.x, lane = tid & 63, w = tid >> 6;

  __shared__ short Xs[64 * 128];
  __shared__ float red[18];

  {
    const int rowslot = tid >> 3, unit = tid & 7;
    #pragma unroll
    for (int rit = 0; rit < 2; ++rit) {
      const int C = rit * 64 + rowslot;
      const sh8 vv = *(const sh8*)(Cs + (((size_t)b * 128 + C) * 512 + t2) * 64 + unit * 8);
      #pragma unroll
      for (int jj = 0; jj < 8; ++jj) {
        const int f2 = unit * 8 + jj;
        *((short*)((char*)Xs + f2 * 256 + ((2 * C) ^ ((f2 & 7) << 4)))) = vv[jj];
      }
    }
  }
  __syncthreads();

  const float alpha = alphap[0];
  fx4 acc[4];
  #pragma unroll
  for (int ni = 0; ni < 4; ++ni) acc[ni] = fx4{0.f, 0.f, 0.f, 0.f};

  #pragma unroll
  for (int ks = 0; ks < 4; ++ks) {
    const int o = w * 16 + (lane & 15);
    const sh8 a = *(const sh8*)(wb + o * 128 + ks * 32 + (lane >> 4) * 8);
    #pragma unroll
    for (int ni = 0; ni < 4; ++ni) {
      const int f2 = ni * 16 + (lane & 15);
      const sh8 bf = *(const sh8*)((const char*)Xs + f2 * 256 +
                     ((ks * 64 + (lane >> 4) * 16) ^ ((f2 & 7) << 4)));
      acc[ni] = mfma_bf16(a, bf, acc[ni]);
    }
  }

  float s0 = 0.f, s1 = 0.f;
  const int ob = w * 16 + (lane >> 4) * 4;
  #pragma unroll
  for (int ni = 0; ni < 4; ++ni)
    #pragma unroll
    for (int r = 0; r < 4; ++r) {
      float v = acc[ni][r] + bias[ob + r];
      v = (v >= 0.f) ? v : alpha * v;
      acc[ni][r] = v;
      s0 += v; s1 += v * v;
    }
  #pragma unroll
  for (int off = 32; off > 0; off >>= 1) { s0 += __shfl_down(s0, off); s1 += __shfl_down(s1, off); }
  if (lane == 0) { red[w * 2] = s0; red[w * 2 + 1] = s1; }
  __syncthreads();
  if (tid == 0) {
    float a0 = 0.f, a1 = 0.f;
    for (int i2 = 0; i2 < 8; ++i2) { a0 += red[2 * i2]; a1 += red[2 * i2 + 1]; }
    const float mu = a0 / 8192.f;
    const float var = a1 / 8192.f - mu * mu;
    red[16] = mu; red[17] = rsqrtf(var + 1e-5f);
  }
  __syncthreads();
  const float mu = red[16], rstd = red[17];

  #pragma unroll
  for (int ni = 0; ni < 4; ++ni) {
    const int f2 = ni * 16 + (lane & 15);
    #pragma unroll
    for (int r = 0; r < 4; ++r) {
      const int o = ob + r;
      const float zz = (acc[ni][r] - mu) * rstd * gamma[o * 64 + f2] + beta[o * 64 + f2];
      Otmpb[(((size_t)b * 128 + o) * 512 + t2) * 64 + f2] = bf16r(zz);
    }
  }
}

// ---------------------------------------------------------------------------
// k_trans: Otmp bf16 [b][o][t2][f2] -> out f32 [b][o][f2][t2]
__global__ __launch_bounds__(256) void k_trans(const short* __restrict__ Otmpb,
                                               float* __restrict__ out)
{
  const int bid = blockIdx.x;
  const int bo = bid >> 3, tt8 = bid & 7;
  const int t20 = tt8 * 64;
  const int tid = threadIdx.x;
  __shared__ float Ltr[64 * 68];

  {
    const int t2l = tid >> 2, u = tid & 3;
    const short* srow = Otmpb + ((size_t)bo * 512 + t20 + t2l) * 64 + u * 16;
    const sh8 v0 = *(const sh8*)(srow);
    const sh8 v1 = *(const sh8*)(srow + 8);
    #pragma unroll
    for (int e = 0; e < 8; ++e) {
      Ltr[(u * 16 + e) * 68 + t2l]     = b2f(v0[e]);
      Ltr[(u * 16 + 8 + e) * 68 + t2l] = b2f(v1[e]);
    }
  }
  __syncthreads();
  {
    const int f2 = tid >> 2, u = tid & 3;
    float* dst = out + ((size_t)bo * 64 + f2) * 512 + t20 + u * 16;
    #pragma unroll
    for (int k = 0; k < 4; ++k)
      *(float4*)(dst + k * 4) = *(const float4*)&Ltr[f2 * 68 + u * 16 + k * 4];
  }
}

// ---------------------------------------------------------------------------
extern "C" void kernel_launch(void* const* d_in, const int* in_sizes, int n_in,
                              void* d_out, int out_size, void* d_ws, size_t ws_size,
                              hipStream_t stream) {
  (void)in_sizes; (void)n_in; (void)out_size;
  const float* x          = (const float*)d_in[0];
  const float* qkv_w      = (const float*)d_in[1];
  const float* qkv_b      = (const float*)d_in[2];
  const float* qkv_alpha  = (const float*)d_in[3];
  const float* qkv_gamma  = (const float*)d_in[4];
  const float* qkv_beta   = (const float*)d_in[5];
  const float* proj_w     = (const float*)d_in[6];
  const float* proj_b     = (const float*)d_in[7];
  const float* proj_alpha = (const float*)d_in[8];
  const float* proj_gamma = (const float*)d_in[9];
  const float* proj_beta  = (const float*)d_in[10];
  float* out = (float*)d_out;

  // ws layout (total 167,903,232 B known safe). NOTE: Cs and Otmpb are each
  // 33,554,432 B (16.8M bf16 elements = 33.5MB — R5/R6 sized this wrong and
  // overlapped them; Otmpb now lives at 0 over dead Qp).
  //  @0        Qp (33.5M) [kA -> k_flash] ; Otmpb (33.5M) [k_proj -> k_trans]
  //  @33.5M    Kp (33.5M) [kA -> k_flash]
  //  @67M      Vt (33.5M) [kA -> k_flash]
  //  @100.7M   Xb (33.5M) [k_xt -> kA] ; Cs (33.5M) [k_flash -> k_proj]
  //  @134.2M   RowB (512KB) + gq/bq/gv/bv + HC   (ends ~134.94M)
  //  @167.77M  qwb, pwb
  //  Pstat (17.8MB) stashed in d_out, fully overwritten by k_trans
  char* ws = (char*)d_ws;
  short* Qp   = (short*)(ws + 0);
  short* Otmpb= (short*)(ws + 0);
  short* Kp   = (short*)(ws + 33554432);
  short* Vt   = (short*)(ws + 67108864);
  short* Xb   = (short*)(ws + 100663296);
  short* Cs   = (short*)(ws + 100663296);
  float* RowB = (float*)(ws + 134217728);
  float* gq   = (float*)(ws + 134742016);
  float* bq   = (float*)(ws + 134807552);
  float* gv   = (float*)(ws + 134873088);
  float* bv   = (float*)(ws + 134905856);
  float* HC   = (float*)(ws + 134938624);
  short* qwb  = (short*)(ws + 167772160);
  short* pwb  = (short*)(ws + 167870464);
  float* Pstat = (float*)d_out;
  if (ws_size < 167903232u) return;

  k_prep<<<200, 256, 0, stream>>>(qkv_w, proj_w, qkv_gamma, qkv_beta,
                                  qwb, pwb, gq, bq, gv, bv, HC);
  k_xt<<<1024, 256, 0, stream>>>(x, Xb);
  kA_qkv<<<1024, 512, 0, stream>>>(Xb, qwb, qkv_b, qkv_alpha, gq, bq,
                                   Qp, Kp, Vt, Pstat);
  k_stats<<<64, 256, 0, stream>>>(Pstat, HC, RowB);
  k_flash<<<512, 256, 0, stream>>>(Qp, Kp, Vt, RowB, gv, bv, HC, Cs);
  k_proj<<<2048, 512, 0, stream>>>(Cs, pwb, proj_b, proj_alpha, proj_gamma, proj_beta, Otmpb);
  k_trans<<<4096, 256, 0, stream>>>(Otmpb, out);
}

// Round 11
// 229.353 us; speedup vs baseline: 2.8410x; 2.8410x over previous
//
#include <hip/hip_runtime.h>
#include <hip/hip_bf16.h>

#define T_ 512

using sh8 = __attribute__((ext_vector_type(8))) short;  // 8 bf16
using fx4 = __attribute__((ext_vector_type(4))) float;  // MFMA acc

__device__ __forceinline__ short bf16r(float x) {
  union { float f; unsigned u; } v; v.f = x;
  unsigned u = v.u;
  u += 0x7fffu + ((u >> 16) & 1u);   // RNE
  return (short)(u >> 16);
}
__device__ __forceinline__ float b2f(short s) {
  union { float f; unsigned u; } v; v.u = ((unsigned)(unsigned short)s) << 16;
  return v.f;
}
__device__ __forceinline__ fx4 mfma_bf16(sh8 a, sh8 b, fx4 c) {
  return __builtin_amdgcn_mfma_f32_16x16x32_bf16(a, b, c, 0, 0, 0);
}

// ---------------------------------------------------------------------------
// k_prep: weights f32->bf16; permuted gamma/beta tables; per-head constants
//   HC[h][4] = {Ggg, Gqb, Gkb, Bbb}.
__global__ __launch_bounds__(256) void k_prep(
    const float* __restrict__ qw, const float* __restrict__ pw,
    const float* __restrict__ gamma, const float* __restrict__ beta,
    short* __restrict__ qwb, short* __restrict__ pwb,
    float* __restrict__ gq, float* __restrict__ bq,
    float* __restrict__ gv, float* __restrict__ bv,
    float* __restrict__ HC)
{
  __shared__ float cred[4][4];
  if (blockIdx.x >= 192) {            // per-head constant blocks
    const int h = blockIdx.x - 192;
    float c0 = 0.f, c1 = 0.f, c2 = 0.f, c3 = 0.f;
    #pragma unroll
    for (int e = 0; e < 4; ++e) {
      const int dp = threadIdx.x * 4 + e;
      const int cl = dp & 15, fq = dp >> 4;
      const float gqv = gamma[(h * 48 + cl) * 64 + fq];
      const float gkv = gamma[(h * 48 + 16 + cl) * 64 + fq];
      const float bqv = beta[(h * 48 + cl) * 64 + fq];
      const float bkv = beta[(h * 48 + 16 + cl) * 64 + fq];
      c0 += gqv * gkv; c1 += gqv * bkv; c2 += gkv * bqv; c3 += bqv * bkv;
    }
    #pragma unroll
    for (int off = 32; off > 0; off >>= 1) {
      c0 += __shfl_down(c0, off); c1 += __shfl_down(c1, off);
      c2 += __shfl_down(c2, off); c3 += __shfl_down(c3, off);
    }
    if ((threadIdx.x & 63) == 0) {
      cred[threadIdx.x >> 6][0] = c0; cred[threadIdx.x >> 6][1] = c1;
      cred[threadIdx.x >> 6][2] = c2; cred[threadIdx.x >> 6][3] = c3;
    }
    __syncthreads();
    if (threadIdx.x < 4) {
      float s = 0.f;
      for (int k2 = 0; k2 < 4; ++k2) s += cred[k2][threadIdx.x];
      HC[h * 4 + threadIdx.x] = s;
    }
    return;
  }
  const int i = blockIdx.x * 256 + threadIdx.x;
  if (i < 49152) qwb[i] = bf16r(qw[i]);
  if (i < 16384) pwb[i] = bf16r(pw[i]);
  if (i < 16384) {
    const int sh = i >> 10, dp = i & 1023;
    const int sect = sh >> 3, h = sh & 7;
    const int gi = (h * 48 + sect * 16 + (dp & 15)) * 64 + (dp >> 4);
    gq[i] = gamma[gi]; bq[i] = beta[gi];
  }
  if (i < 8192) {
    const int h = i >> 10, d = i & 1023;
    const int gi = (h * 48 + 32 + (d >> 6)) * 64 + (d & 63);
    gv[i] = gamma[gi]; bv[i] = beta[gi];
  }
}

// ---------------------------------------------------------------------------
// k_xt: x f32 [b][c][f][t] -> Xb bf16 [(b*64+f)*16 + c/8][t][c%8]
__global__ __launch_bounds__(256) void k_xt(const float* __restrict__ x,
                                            short* __restrict__ Xb)
{
  const int bid = blockIdx.x;
  const int b = bid >> 8, f = (bid >> 2) & 63, tt = bid & 3;
  const int tid = threadIdx.x;

  __shared__ short Xraw[128 * 128];   // [c][tl], 256B pitch, swz ((c&7)<<4)

  {
    const int tq = (tid & 31) * 4, c0 = tid >> 5;
    const float* xp = x + (((size_t)(b * 128 + c0) * 64 + f) * 512) + tt * 128 + tq;
    #pragma unroll
    for (int p = 0; p < 16; ++p) {
      const int c = c0 + p * 8;
      const float4 fv = *(const float4*)xp;
      xp += 262144;
      short4 o;
      o.x = bf16r(fv.x); o.y = bf16r(fv.y); o.z = bf16r(fv.z); o.w = bf16r(fv.w);
      *(short4*)((char*)Xraw + c * 256 + ((2 * tq) ^ ((c & 7) << 4))) = o;
    }
  }
  __syncthreads();

  short* xb = Xb + (size_t)((b * 64 + f) * 16) * 4096;
  #pragma unroll
  for (int it = 0; it < 8; ++it) {
    const int chunk = tid + it * 256;
    const int c8 = chunk >> 7, tl = chunk & 127;
    sh8 o;
    #pragma unroll
    for (int e = 0; e < 8; ++e)
      o[e] = *((const short*)((const char*)Xraw + (c8 * 8 + e) * 256 + ((2 * tl) ^ (e << 4))));
    *(sh8*)(xb + ((size_t)c8 * 512 + tt * 128 + tl) * 8) = o;
  }
}

// ---------------------------------------------------------------------------
// kA: per (b, f, tt): Y[384,128] = W @ X; bias+PReLU; stats; stores
//   Q~/K~ packed planes Qp4/Kp4 [bh][dq=d'/4][t]{4 shorts} (128B runs),
//   V raw [bh][d][t].
__global__ __launch_bounds__(512) void kA_qkv(
    const short* __restrict__ Xb, const short* __restrict__ wb,
    const float* __restrict__ bias, const float* __restrict__ alphap,
    const float* __restrict__ gq, const float* __restrict__ bq,
    short* __restrict__ Qp4, short* __restrict__ Kp4, short* __restrict__ Vt,
    float* __restrict__ Pstat)
{
  const int bid = blockIdx.x;
  const int b = bid >> 8, f = (bid >> 2) & 63, tt = bid & 3;
  const int tid = threadIdx.x, lane = tid & 63, w = tid >> 6;

  __shared__ float psum[8 * 8 * 16 * 6];   // [w][ni][l16][ch], 24KB

  fx4 acc[3][8];
  #pragma unroll
  for (int mi = 0; mi < 3; ++mi)
    #pragma unroll
    for (int ni = 0; ni < 8; ++ni) acc[mi][ni] = fx4{0.f, 0.f, 0.f, 0.f};

  const short* xb = Xb + (size_t)((b * 64 + f) * 16) * 4096;

  #pragma unroll
  for (int ks = 0; ks < 4; ++ks) {
    sh8 a[3];
    #pragma unroll
    for (int mi = 0; mi < 3; ++mi) {
      const int o = w * 48 + mi * 16 + (lane & 15);
      a[mi] = *(const sh8*)(wb + o * 128 + ks * 32 + (lane >> 4) * 8);
    }
    #pragma unroll
    for (int ni = 0; ni < 8; ++ni) {
      const sh8 bf = *(const sh8*)(xb + ((size_t)(ks * 4 + (lane >> 4)) * 512 +
                                         tt * 128 + ni * 16 + (lane & 15)) * 8);
      #pragma unroll
      for (int mi = 0; mi < 3; ++mi)
        acc[mi][ni] = mfma_bf16(a[mi], bf, acc[mi][ni]);
    }
  }

  float gqq[4], gqk[4], bqq[4], bqk[4];
  #pragma unroll
  for (int r = 0; r < 4; ++r) {
    const int dp = f * 16 + (lane >> 4) * 4 + r;
    gqq[r] = gq[w * 1024 + dp];
    gqk[r] = gq[(8 + w) * 1024 + dp];
    bqq[r] = bq[w * 1024 + dp];
    bqk[r] = bq[(8 + w) * 1024 + dp];
  }

  const float alpha = alphap[0];
  #pragma unroll
  for (int ni = 0; ni < 8; ++ni) {
    float t0 = 0.f, t1 = 0.f, taq = 0.f, tuq = 0.f, tak = 0.f, tuk = 0.f;
    #pragma unroll
    for (int mi = 0; mi < 3; ++mi)
      #pragma unroll
      for (int r = 0; r < 4; ++r) {
        const int o = w * 48 + mi * 16 + (lane >> 4) * 4 + r;
        float v = acc[mi][ni][r] + bias[o];
        v = (v >= 0.f) ? v : alpha * v;
        acc[mi][ni][r] = v;
        t0 += v; t1 += v * v;
        if (mi == 0) { const float qt = v * gqq[r]; taq += qt * gqk[r]; tuq += qt * bqk[r]; }
        if (mi == 1) { const float kt = v * gqk[r]; tak += kt * gqq[r]; tuk += kt * bqq[r]; }
      }
    t0 += __shfl_down(t0, 32); t1 += __shfl_down(t1, 32);
    taq += __shfl_down(taq, 32); tuq += __shfl_down(tuq, 32);
    tak += __shfl_down(tak, 32); tuk += __shfl_down(tuk, 32);
    t0 += __shfl_down(t0, 16); t1 += __shfl_down(t1, 16);
    taq += __shfl_down(taq, 16); tuq += __shfl_down(tuq, 16);
    tak += __shfl_down(tak, 16); tuk += __shfl_down(tuk, 16);
    if (lane < 16) {
      float* ps = &psum[((w * 8 + ni) * 16 + lane) * 6];
      ps[0] = t0; ps[1] = t1; ps[2] = taq; ps[3] = tuq; ps[4] = tak; ps[5] = tuk;
    }
  }
  __syncthreads();

  if (tid < 256) {
    const int col = tid & 127, s = tid >> 7;
    const int ni = col >> 4, l = col & 15;
    float a0 = 0.f;
    #pragma unroll
    for (int ww = 0; ww < 8; ++ww) a0 += psum[((ww * 8 + ni) * 16 + l) * 6 + s];
    Pstat[(size_t)s * 131072 + (size_t)b * 32768 + (size_t)f * 512 + tt * 128 + col] = a0;
  }
  #pragma unroll
  for (int p = 0; p < 8; ++p) {
    const int idx = p * 512 + tid;
    const int col = idx & 127, wc = idx >> 7;
    const int ww = wc >> 2, ch = wc & 3;
    const int ni = col >> 4, l = col & 15;
    Pstat[(size_t)(2 + ww * 4 + ch) * 131072 + (size_t)b * 32768 +
          (size_t)f * 512 + tt * 128 + col] = psum[((ww * 8 + ni) * 16 + l) * 6 + 2 + ch];
  }

  // stores: Qp4/Kp4 packed planes (128B runs per 16 lanes); Vt [d][t]
  const int bh = b * 8 + w;
  const int dq = f * 4 + (lane >> 4);
  #pragma unroll
  for (int mi = 0; mi < 2; ++mi) {
    short* dstp = (mi ? Kp4 : Qp4) + ((size_t)(bh * 256 + dq) * 512 + tt * 128) * 4;
    #pragma unroll
    for (int ni = 0; ni < 8; ++ni) {
      const int tl = ni * 16 + (lane & 15);
      float v0 = acc[mi][ni][0] * (mi == 0 ? gqq[0] : gqk[0]);
      float v1 = acc[mi][ni][1] * (mi == 0 ? gqq[1] : gqk[1]);
      float v2 = acc[mi][ni][2] * (mi == 0 ? gqq[2] : gqk[2]);
      float v3 = acc[mi][ni][3] * (mi == 0 ? gqq[3] : gqk[3]);
      uint2 pk;
      pk.x = (unsigned)(unsigned short)bf16r(v0) | ((unsigned)(unsigned short)bf16r(v1) << 16);
      pk.y = (unsigned)(unsigned short)bf16r(v2) | ((unsigned)(unsigned short)bf16r(v3) << 16);
      *(uint2*)(dstp + tl * 4) = pk;
    }
  }
  #pragma unroll
  for (int ni = 0; ni < 8; ++ni)
    #pragma unroll
    for (int r = 0; r < 4; ++r) {
      const int cl = (lane >> 4) * 4 + r;
      Vt[((size_t)bh * 1024 + cl * 64 + f) * 512 + tt * 128 + ni * 16 + (lane & 15)] =
          bf16r(acc[2][ni][r]);
    }
}

// ---------------------------------------------------------------------------
// k_stats: RowB[bh][t][8] = {rs, rm, rs*aq, rs*uq - rm*Gqb, rs*ak, rs*uk - rm*Gkb, 0, 0}
__global__ __launch_bounds__(256) void k_stats(const float* __restrict__ Pstat,
                                               const float* __restrict__ HC,
                                               float* __restrict__ RowB)
{
  const int idx = blockIdx.x * 256 + threadIdx.x;   // 16384
  const int b = idx >> 12, h = (idx >> 9) & 7, t = idx & 511;
  const float* P0 = Pstat + (size_t)b * 32768 + t;
  float s0 = 0.f, s1 = 0.f, aq = 0.f, uq = 0.f, ak = 0.f, uk = 0.f;
  for (int fq = 0; fq < 64; ++fq) {
    const size_t o = (size_t)fq * 512;
    s0 += P0[o];
    s1 += P0[(size_t)131072 + o];
    aq += P0[(size_t)(2 + h * 4 + 0) * 131072 + o];
    uq += P0[(size_t)(2 + h * 4 + 1) * 131072 + o];
    ak += P0[(size_t)(2 + h * 4 + 2) * 131072 + o];
    uk += P0[(size_t)(2 + h * 4 + 3) * 131072 + o];
  }
  const float mu = s0 * (1.f / 24576.f);
  const float var = s1 * (1.f / 24576.f) - mu * mu;
  const float rs = rsqrtf(var + 1e-5f);
  const float rm = rs * mu;
  float* o8 = RowB + ((size_t)(b * 8 + h) * 512 + t) * 8;
  o8[0] = rs;
  o8[1] = rm;
  o8[2] = rs * aq;
  o8[3] = rs * uq - rm * HC[h * 4 + 1];
  o8[4] = rs * ak;
  o8[5] = rs * uk - rm * HC[h * 4 + 2];
  o8[6] = 0.f; o8[7] = 0.f;
}

// ---------------------------------------------------------------------------
// k_qk: S = affine-corrected (Q~.K~)/32, lower-tri 128x128 tiles. Fragments
//   loaded DIRECTLY from packed global planes (L2-hot); no LDS staging.
__global__ __launch_bounds__(256) void k_qk(
    const short* __restrict__ Qp4, const short* __restrict__ Kp4,
    const float* __restrict__ RowB, const float* __restrict__ HC,
    float* __restrict__ S)
{
  const int bid = blockIdx.x;
  const int bh = bid / 10;
  const int j = bid - bh * 10;
  const int qi = (j >= 6) ? 3 : (j >= 3) ? 2 : (j >= 1) ? 1 : 0;
  const int ki = j - qi * (qi + 1) / 2;
  const int b = bh >> 3, h = bh & 7;
  const int tid = threadIdx.x, lane = tid & 63, w = tid >> 6;
  const int wm = w >> 1, wn = w & 1;

  __shared__ float4 qb[128];   // {rs, rm, Aq, Uq}
  __shared__ float4 kb[128];   // {rs, rm, Ak, Uk}

  if (tid < 128) {
    const float* rb = RowB + ((size_t)(b * 8 + h) * 512 + qi * 128 + tid) * 8;
    qb[tid] = float4{rb[0], rb[1], rb[2], rb[3]};
  } else {
    const float* rb = RowB + ((size_t)(b * 8 + h) * 512 + ki * 128 + (tid - 128)) * 8;
    kb[tid - 128] = float4{rb[0], rb[1], rb[4], rb[5]};
  }
  __syncthreads();

  const float Ggg = HC[h * 4 + 0], Bbb = HC[h * 4 + 3];

  // per-mi/ni fragment row pointers (t fixed; dq advances with kc)
  const short* Qbase = Qp4 + (size_t)bh * 256 * 512 * 4;
  const short* Kbase = Kp4 + (size_t)bh * 256 * 512 * 4;
  const short* pA[4];
  const short* pB[4];
  #pragma unroll
  for (int mi = 0; mi < 4; ++mi) {
    const int t = qi * 128 + wm * 64 + mi * 16 + (lane & 15);
    pA[mi] = Qbase + ((size_t)((lane >> 4) * 2) * 512 + t) * 4;
    const int t2 = ki * 128 + wn * 64 + mi * 16 + (lane & 15);
    pB[mi] = Kbase + ((size_t)((lane >> 4) * 2) * 512 + t2) * 4;
  }

  fx4 acc[4][4];
  #pragma unroll
  for (int mi = 0; mi < 4; ++mi)
    #pragma unroll
    for (int ni = 0; ni < 4; ++ni) acc[mi][ni] = fx4{0.f, 0.f, 0.f, 0.f};

  for (int kc = 0; kc < 32; ++kc) {   // 32 d' per step; dq stride 8 planes
    const size_t off = (size_t)kc * 8 * 512 * 4;   // shorts
    sh8 a[4], bb[4];
    #pragma unroll
    for (int mi = 0; mi < 4; ++mi) {
      const uint2 x0 = *(const uint2*)(pA[mi] + off);
      const uint2 x1 = *(const uint2*)(pA[mi] + off + 2048);
      union { unsigned u[4]; sh8 s; } c; c.u[0] = x0.x; c.u[1] = x0.y; c.u[2] = x1.x; c.u[3] = x1.y;
      a[mi] = c.s;
    }
    #pragma unroll
    for (int ni = 0; ni < 4; ++ni) {
      const uint2 x0 = *(const uint2*)(pB[ni] + off);
      const uint2 x1 = *(const uint2*)(pB[ni] + off + 2048);
      union { unsigned u[4]; sh8 s; } c; c.u[0] = x0.x; c.u[1] = x0.y; c.u[2] = x1.x; c.u[3] = x1.y;
      bb[ni] = c.s;
    }
    #pragma unroll
    for (int mi = 0; mi < 4; ++mi)
      #pragma unroll
      for (int ni = 0; ni < 4; ++ni)
        acc[mi][ni] = mfma_bf16(a[mi], bb[ni], acc[mi][ni]);
  }

  float* Sg = S + (size_t)bh * 262144;
  const int q0 = qi * 128 + wm * 64, k0 = ki * 128 + wn * 64;
  #pragma unroll
  for (int mi = 0; mi < 4; ++mi)
    #pragma unroll
    for (int ni = 0; ni < 4; ++ni) {
      const int kl = wn * 64 + ni * 16 + (lane & 15);
      const float4 kv = kb[kl];
      const int kc2 = k0 + ni * 16 + (lane & 15);
      #pragma unroll
      for (int r = 0; r < 4; ++r) {
        const int qll = wm * 64 + mi * 16 + (lane >> 4) * 4 + r;
        const float4 qv = qb[qll];
        float s = acc[mi][ni][r];
        s = qv.x * kv.x * s - qv.z * kv.y - qv.y * kv.z + (qv.y * kv.y) * Ggg
            + qv.w + kv.w + Bbb;
        Sg[(size_t)(q0 + mi * 16 + (lane >> 4) * 4 + r) * 512 + kc2] = s * 0.03125f;
      }
    }
}

// ---------------------------------------------------------------------------
// k_softmax: causal softmax; emits P'' = p * rs_k / L (bf16, zeros above diag)
//   and saq' = sum(p * rm_k)/L into RowB[..][6].
__global__ __launch_bounds__(256) void k_softmax(const float* __restrict__ S,
                                                 short* __restrict__ Pb,
                                                 float* __restrict__ RowB)
{
  const int row = blockIdx.x * 4 + (threadIdx.x >> 6);
  const int lane = threadIdx.x & 63;
  const int bh = row >> 9, q = row & 511;
  const float* Sr = S + (size_t)bh * 262144 + (size_t)q * 512;
  short* Pr = Pb + (size_t)bh * 262144 + (size_t)q * 512;
  const float* rbk = RowB + (size_t)bh * 512 * 8;
  const int n = q + 1;
  float v[8], rsx[8], rmx[8];
  float mx = -1e30f;
  #pragma unroll
  for (int i = 0; i < 8; ++i) {
    const int k = lane + i * 64;
    v[i] = (k < n) ? Sr[k] : -1e30f;
    mx = fmaxf(mx, v[i]);
    const float2 rr = *(const float2*)(rbk + (size_t)k * 8);
    rsx[i] = rr.x; rmx[i] = rr.y;
  }
  #pragma unroll
  for (int off = 32; off > 0; off >>= 1) mx = fmaxf(mx, __shfl_xor(mx, off));
  float sum = 0.f, saq = 0.f;
  #pragma unroll
  for (int i = 0; i < 8; ++i) {
    const float e = (v[i] > -1e29f) ? __expf(v[i] - mx) : 0.f;
    v[i] = e; sum += e; saq += e * rmx[i];
  }
  #pragma unroll
  for (int off = 32; off > 0; off >>= 1) {
    sum += __shfl_xor(sum, off); saq += __shfl_xor(saq, off);
  }
  const float inv = 1.f / sum;
  #pragma unroll
  for (int i = 0; i < 8; ++i) Pr[lane + i * 64] = bf16r(v[i] * rsx[i] * inv);
  if (lane == 0) RowB[((size_t)bh * 512 + q) * 8 + 6] = saq * inv;
}

// ---------------------------------------------------------------------------
// k_pv: ctx = P'' @ V(raw), BK=64; epilogue gv*(acc - saq') + bv; -> Cs.
__global__ __launch_bounds__(256) void k_pv(
    const short* __restrict__ Pb, const short* __restrict__ Vt,
    const float* __restrict__ RowB, const float* __restrict__ gvt,
    const float* __restrict__ bvt, short* __restrict__ Cs)
{
  const int bid = blockIdx.x;
  const int bh = bid >> 5, qi = (bid >> 3) & 3, dt = bid & 7;
  const int b = bh >> 3, h = bh & 7;
  const int tid = threadIdx.x, lane = tid & 63, w = tid >> 6;
  const int wm = w >> 1, wn = w & 1;

  __shared__ char smem[32768];
  short* Ps = (short*)smem;                // [128 q][64 k], 128B pitch
  short* Vs = (short*)(smem + 16384);      // [128 d][64 k]
  short* ctile = (short*)smem;             // [128 d][128 q] reuse after loop
  __shared__ float saqv[128];

  const short* Pg = Pb + ((size_t)bh * 512 + qi * 128) * 512;
  const short* Vg = Vt + ((size_t)bh * 1024 + dt * 128) * 512;

  if (tid < 128)
    saqv[tid] = RowB[((size_t)bh * 512 + qi * 128 + tid) * 8 + 6];

  const int rowslot = tid >> 3, unit = tid & 7;

  fx4 acc[4][4];
  #pragma unroll
  for (int mi = 0; mi < 4; ++mi)
    #pragma unroll
    for (int ni = 0; ni < 4; ++ni) acc[mi][ni] = fx4{0.f, 0.f, 0.f, 0.f};

  const int nks = (qi + 1) * 2;
  for (int ks = 0; ks < nks; ++ks) {
    __syncthreads();
    #pragma unroll
    for (int rit = 0; rit < 4; ++rit) {
      const int rr2 = rit * 32 + rowslot;
      const sh8 p = *(const sh8*)(Pg + (size_t)rr2 * 512 + ks * 64 + unit * 8);
      *(sh8*)((char*)Ps + rr2 * 128 + ((unit * 16) ^ ((rr2 & 7) << 4))) = p;
      const sh8 vv = *(const sh8*)(Vg + (size_t)rr2 * 512 + ks * 64 + unit * 8);
      *(sh8*)((char*)Vs + rr2 * 128 + ((unit * 16) ^ ((rr2 & 7) << 4))) = vv;
    }
    __syncthreads();
    #pragma unroll
    for (int ksub = 0; ksub < 2; ++ksub) {
      sh8 a[4], bb[4];
      #pragma unroll
      for (int mi = 0; mi < 4; ++mi) {
        const int r2 = wm * 64 + mi * 16 + (lane & 15);
        a[mi] = *(const sh8*)((const char*)Ps + r2 * 128 +
                ((ksub * 64 + (lane >> 4) * 16) ^ ((r2 & 7) << 4)));
      }
      #pragma unroll
      for (int ni = 0; ni < 4; ++ni) {
        const int r2 = wn * 64 + ni * 16 + (lane & 15);
        bb[ni] = *(const sh8*)((const char*)Vs + r2 * 128 +
                 ((ksub * 64 + (lane >> 4) * 16) ^ ((r2 & 7) << 4)));
      }
      #pragma unroll
      for (int mi = 0; mi < 4; ++mi)
        #pragma unroll
        for (int ni = 0; ni < 4; ++ni)
          acc[mi][ni] = mfma_bf16(a[mi], bb[ni], acc[mi][ni]);
    }
  }
  __syncthreads();   // protect Ps/Vs reads before ctile overwrite

  #pragma unroll
  for (int mi = 0; mi < 4; ++mi)
    #pragma unroll
    for (int ni = 0; ni < 4; ++ni) {
      const int ql = wm * 64 + mi * 16 + (lane >> 4) * 4;
      const int dl = wn * 64 + ni * 16 + (lane & 15);
      const float gvv = gvt[h * 1024 + dt * 128 + dl];
      const float bvv = bvt[h * 1024 + dt * 128 + dl];
      const int swz = (dl & 7) << 4;
      #pragma unroll
      for (int r = 0; r < 4; ++r) {
        const float o = gvv * (acc[mi][ni][r] - saqv[ql + r]) + bvv;
        ctile[(dl * 256 + ((2 * (ql + r)) ^ swz)) >> 1] = bf16r(o);
      }
    }
  __syncthreads();

  // scrambled write: c[b][C][t2][f2] in 128B f2-runs
  const int cl_loc = tid >> 7, fq = (tid >> 1) & 63, tg_loc = tid & 1;
  const int C = h * 16 + dt * 2 + cl_loc;
  const int t2 = fq * 8 + qi * 2 + tg_loc;
  const int dl = cl_loc * 64 + fq;
  const int swz = (dl & 7) << 4;
  short* dst = Cs + (((size_t)b * 128 + C) * 512 + t2) * 64;
  #pragma unroll
  for (int jj = 0; jj < 8; ++jj) {
    const sh8 vv = *(const sh8*)((const char*)ctile + dl * 256 + ((tg_loc * 128 + jj * 16) ^ swz));
    *(sh8*)(dst + jj * 8) = vv;
  }
}

// ---------------------------------------------------------------------------
// k_proj: per (b,t2): Y[128,64] = Wp @ C; bias+PReLU+LN; -> Otmp bf16 [b][o][t2][f2]
__global__ __launch_bounds__(512) void k_proj(
    const short* __restrict__ Cs, const short* __restrict__ wb,
    const float* __restrict__ bias, const float* __restrict__ alphap,
    const float* __restrict__ gamma, const float* __restrict__ beta,
    short* __restrict__ Otmpb)
{
  const int bid = blockIdx.x;
  const int b = bid >> 9, t2 = bid & 511;
  const int tid = threadIdx.x, lane = tid & 63, w = tid >> 6;

  __shared__ short Xs[64 * 128];
  __shared__ float red[18];

  {
    const int rowslot = tid >> 3, unit = tid & 7;
    #pragma unroll
    for (int rit = 0; rit < 2; ++rit) {
      const int C = rit * 64 + rowslot;
      const sh8 vv = *(const sh8*)(Cs + (((size_t)b * 128 + C) * 512 + t2) * 64 + unit * 8);
      #pragma unroll
      for (int jj = 0; jj < 8; ++jj) {
        const int f2 = unit * 8 + jj;
        *((short*)((char*)Xs + f2 * 256 + ((2 * C) ^ ((f2 & 7) << 4)))) = vv[jj];
      }
    }
  }
  __syncthreads();

  const float alpha = alphap[0];
  fx4 acc[4];
  #pragma unroll
  for (int ni = 0; ni < 4; ++ni) acc[ni] = fx4{0.f, 0.f, 0.f, 0.f};

  #pragma unroll
  for (int ks = 0; ks < 4; ++ks) {
    const int o = w * 16 + (lane & 15);
    const sh8 a = *(const sh8*)(wb + o * 128 + ks * 32 + (lane >> 4) * 8);
    #pragma unroll
    for (int ni = 0; ni < 4; ++ni) {
      const int f2 = ni * 16 + (lane & 15);
      const sh8 bf = *(const sh8*)((const char*)Xs + f2 * 256 +
                     ((ks * 64 + (lane >> 4) * 16) ^ ((f2 & 7) << 4)));
      acc[ni] = mfma_bf16(a, bf, acc[ni]);
    }
  }

  float s0 = 0.f, s1 = 0.f;
  const int ob = w * 16 + (lane >> 4) * 4;
  #pragma unroll
  for (int ni = 0; ni < 4; ++ni)
    #pragma unroll
    for (int r = 0; r < 4; ++r) {
      float v = acc[ni][r] + bias[ob + r];
      v = (v >= 0.f) ? v : alpha * v;
      acc[ni][r] = v;
      s0 += v; s1 += v * v;
    }
  #pragma unroll
  for (int off = 32; off > 0; off >>= 1) { s0 += __shfl_down(s0, off); s1 += __shfl_down(s1, off); }
  if (lane == 0) { red[w * 2] = s0; red[w * 2 + 1] = s1; }
  __syncthreads();
  if (tid == 0) {
    float a0 = 0.f, a1 = 0.f;
    for (int i2 = 0; i2 < 8; ++i2) { a0 += red[2 * i2]; a1 += red[2 * i2 + 1]; }
    const float mu = a0 / 8192.f;
    const float var = a1 / 8192.f - mu * mu;
    red[16] = mu; red[17] = rsqrtf(var + 1e-5f);
  }
  __syncthreads();
  const float mu = red[16], rstd = red[17];

  #pragma unroll
  for (int ni = 0; ni < 4; ++ni) {
    const int f2 = ni * 16 + (lane & 15);
    #pragma unroll
    for (int r = 0; r < 4; ++r) {
      const int o = ob + r;
      const float zz = (acc[ni][r] - mu) * rstd * gamma[o * 64 + f2] + beta[o * 64 + f2];
      Otmpb[(((size_t)b * 128 + o) * 512 + t2) * 64 + f2] = bf16r(zz);
    }
  }
}

// ---------------------------------------------------------------------------
// k_trans: Otmp bf16 [b][o][t2][f2] -> out f32 [b][o][f2][t2]
__global__ __launch_bounds__(256) void k_trans(const short* __restrict__ Otmpb,
                                               float* __restrict__ out)
{
  const int bid = blockIdx.x;
  const int bo = bid >> 3, tt8 = bid & 7;
  const int t20 = tt8 * 64;
  const int tid = threadIdx.x;
  __shared__ float Ltr[64 * 68];

  {
    const int t2l = tid >> 2, u = tid & 3;
    const short* srow = Otmpb + ((size_t)bo * 512 + t20 + t2l) * 64 + u * 16;
    const sh8 v0 = *(const sh8*)(srow);
    const sh8 v1 = *(const sh8*)(srow + 8);
    #pragma unroll
    for (int e = 0; e < 8; ++e) {
      Ltr[(u * 16 + e) * 68 + t2l]     = b2f(v0[e]);
      Ltr[(u * 16 + 8 + e) * 68 + t2l] = b2f(v1[e]);
    }
  }
  __syncthreads();
  {
    const int f2 = tid >> 2, u = tid & 3;
    float* dst = out + ((size_t)bo * 64 + f2) * 512 + t20 + u * 16;
    #pragma unroll
    for (int k = 0; k < 4; ++k)
      *(float4*)(dst + k * 4) = *(const float4*)&Ltr[f2 * 68 + u * 16 + k * 4];
  }
}

// ---------------------------------------------------------------------------
extern "C" void kernel_launch(void* const* d_in, const int* in_sizes, int n_in,
                              void* d_out, int out_size, void* d_ws, size_t ws_size,
                              hipStream_t stream) {
  (void)in_sizes; (void)n_in; (void)out_size;
  const float* x          = (const float*)d_in[0];
  const float* qkv_w      = (const float*)d_in[1];
  const float* qkv_b      = (const float*)d_in[2];
  const float* qkv_alpha  = (const float*)d_in[3];
  const float* qkv_gamma  = (const float*)d_in[4];
  const float* qkv_beta   = (const float*)d_in[5];
  const float* proj_w     = (const float*)d_in[6];
  const float* proj_b     = (const float*)d_in[7];
  const float* proj_alpha = (const float*)d_in[8];
  const float* proj_gamma = (const float*)d_in[9];
  const float* proj_beta  = (const float*)d_in[10];
  float* out = (float*)d_out;

  // ws layout (total 167,903,232 B known safe); all regions disjoint per lifetime:
  //  @0        Qp4 (33.5M) [kA -> k_qk]   ; Cs (33.5M) [k_pv -> k_proj]
  //  @33.5M    Kp4 (33.5M) [kA -> k_qk]   ; Otmpb (33.5M) [k_proj -> k_trans]
  //  @67M      Vt  (33.5M) [kA -> k_pv]
  //  @100.7M   Xb  (33.5M) [k_xt -> kA]   ; S f32 (33.5M) [k_qk -> k_softmax]
  //  @134.2M   Pb  (16.8M) [k_softmax -> k_pv]
  //  @150.99M  RowB (512K); gq/bq (64K ea); gv/bv (32K ea); HC
  //  @167.77M  qwb (96K), pwb (32K)
  //  Pstat (17.8M) in d_out, fully overwritten by k_trans.
  char* ws = (char*)d_ws;
  short* Qp4  = (short*)(ws + 0);
  short* Cs   = (short*)(ws + 0);
  short* Kp4  = (short*)(ws + 33554432);
  short* Otmpb= (short*)(ws + 33554432);
  short* Vt   = (short*)(ws + 67108864);
  short* Xb   = (short*)(ws + 100663296);
  float* S    = (float*)(ws + 100663296);
  short* Pb   = (short*)(ws + 134217728);
  float* RowB = (float*)(ws + 150994944);
  float* gq   = (float*)(ws + 151519232);
  float* bq   = (float*)(ws + 151584768);
  float* gv   = (float*)(ws + 151650304);
  float* bv   = (float*)(ws + 151683072);
  float* HC   = (float*)(ws + 151715840);
  short* qwb  = (short*)(ws + 167772160);
  short* pwb  = (short*)(ws + 167870464);
  float* Pstat = (float*)d_out;
  if (ws_size < 167903232u) return;

  k_prep<<<200, 256, 0, stream>>>(qkv_w, proj_w, qkv_gamma, qkv_beta,
                                  qwb, pwb, gq, bq, gv, bv, HC);
  k_xt<<<1024, 256, 0, stream>>>(x, Xb);
  kA_qkv<<<1024, 512, 0, stream>>>(Xb, qwb, qkv_b, qkv_alpha, gq, bq,
                                   Qp4, Kp4, Vt, Pstat);
  k_stats<<<64, 256, 0, stream>>>(Pstat, HC, RowB);
  k_qk<<<320, 256, 0, stream>>>(Qp4, Kp4, RowB, HC, S);
  k_softmax<<<4096, 256, 0, stream>>>(S, Pb, RowB);
  k_pv<<<1024, 256, 0, stream>>>(Pb, Vt, RowB, gv, bv, Cs);
  k_proj<<<2048, 512, 0, stream>>>(Cs, pwb, proj_b, proj_alpha, proj_gamma, proj_beta, Otmpb);
  k_trans<<<4096, 256, 0, stream>>>(Otmpb, out);
}

// Round 12
// 228.593 us; speedup vs baseline: 2.8505x; 1.0033x over previous
//
#include <hip/hip_runtime.h>
#include <hip/hip_bf16.h>

#define T_ 512

using sh8 = __attribute__((ext_vector_type(8))) short;  // 8 bf16
using fx4 = __attribute__((ext_vector_type(4))) float;  // MFMA acc

__device__ __forceinline__ short bf16r(float x) {
  union { float f; unsigned u; } v; v.f = x;
  unsigned u = v.u;
  u += 0x7fffu + ((u >> 16) & 1u);   // RNE
  return (short)(u >> 16);
}
__device__ __forceinline__ float b2f(short s) {
  union { float f; unsigned u; } v; v.u = ((unsigned)(unsigned short)s) << 16;
  return v.f;
}
// HW packed f32->bf16 (RNE, same rounding as bf16r): low16=bf16(a), high16=bf16(b)
__device__ __forceinline__ unsigned pk_bf16(float a, float b) {
  unsigned r;
  asm("v_cvt_pk_bf16_f32 %0, %1, %2" : "=v"(r) : "v"(a), "v"(b));
  return r;
}
__device__ __forceinline__ fx4 mfma_bf16(sh8 a, sh8 b, fx4 c) {
  return __builtin_amdgcn_mfma_f32_16x16x32_bf16(a, b, c, 0, 0, 0);
}

// ---------------------------------------------------------------------------
// k_prep: weights f32->bf16; permuted gamma/beta tables; per-head constants
//   HC[h][4] = {Ggg, Gqb, Gkb, Bbb}.
__global__ __launch_bounds__(256) void k_prep(
    const float* __restrict__ qw, const float* __restrict__ pw,
    const float* __restrict__ gamma, const float* __restrict__ beta,
    short* __restrict__ qwb, short* __restrict__ pwb,
    float* __restrict__ gq, float* __restrict__ bq,
    float* __restrict__ gv, float* __restrict__ bv,
    float* __restrict__ HC)
{
  __shared__ float cred[4][4];
  if (blockIdx.x >= 192) {            // per-head constant blocks
    const int h = blockIdx.x - 192;
    float c0 = 0.f, c1 = 0.f, c2 = 0.f, c3 = 0.f;
    #pragma unroll
    for (int e = 0; e < 4; ++e) {
      const int dp = threadIdx.x * 4 + e;
      const int cl = dp & 15, fq = dp >> 4;
      const float gqv = gamma[(h * 48 + cl) * 64 + fq];
      const float gkv = gamma[(h * 48 + 16 + cl) * 64 + fq];
      const float bqv = beta[(h * 48 + cl) * 64 + fq];
      const float bkv = beta[(h * 48 + 16 + cl) * 64 + fq];
      c0 += gqv * gkv; c1 += gqv * bkv; c2 += gkv * bqv; c3 += bqv * bkv;
    }
    #pragma unroll
    for (int off = 32; off > 0; off >>= 1) {
      c0 += __shfl_down(c0, off); c1 += __shfl_down(c1, off);
      c2 += __shfl_down(c2, off); c3 += __shfl_down(c3, off);
    }
    if ((threadIdx.x & 63) == 0) {
      cred[threadIdx.x >> 6][0] = c0; cred[threadIdx.x >> 6][1] = c1;
      cred[threadIdx.x >> 6][2] = c2; cred[threadIdx.x >> 6][3] = c3;
    }
    __syncthreads();
    if (threadIdx.x < 4) {
      float s = 0.f;
      for (int k2 = 0; k2 < 4; ++k2) s += cred[k2][threadIdx.x];
      HC[h * 4 + threadIdx.x] = s;
    }
    return;
  }
  const int i = blockIdx.x * 256 + threadIdx.x;
  if (i < 49152) qwb[i] = bf16r(qw[i]);
  if (i < 16384) pwb[i] = bf16r(pw[i]);
  if (i < 16384) {
    const int sh = i >> 10, dp = i & 1023;
    const int sect = sh >> 3, h = sh & 7;
    const int gi = (h * 48 + sect * 16 + (dp & 15)) * 64 + (dp >> 4);
    gq[i] = gamma[gi]; bq[i] = beta[gi];
  }
  if (i < 8192) {
    const int h = i >> 10, d = i & 1023;
    const int gi = (h * 48 + 32 + (d >> 6)) * 64 + (d & 63);
    gv[i] = gamma[gi]; bv[i] = beta[gi];
  }
}

// ---------------------------------------------------------------------------
// k_xt: x f32 [b][c][f][t] -> Xb bf16 [(b*64+f)*16 + c/8][t][c%8]
__global__ __launch_bounds__(256) void k_xt(const float* __restrict__ x,
                                            short* __restrict__ Xb)
{
  const int bid = blockIdx.x;
  const int b = bid >> 8, f = (bid >> 2) & 63, tt = bid & 3;
  const int tid = threadIdx.x;

  __shared__ short Xraw[128 * 128];   // [c][tl], 256B pitch, swz ((c&7)<<4)

  {
    const int tq = (tid & 31) * 4, c0 = tid >> 5;
    const float* xp = x + (((size_t)(b * 128 + c0) * 64 + f) * 512) + tt * 128 + tq;
    #pragma unroll
    for (int p = 0; p < 16; ++p) {
      const int c = c0 + p * 8;
      const float4 fv = *(const float4*)xp;
      xp += 262144;
      union { unsigned u[2]; short4 s4; } pk;
      pk.u[0] = pk_bf16(fv.x, fv.y);
      pk.u[1] = pk_bf16(fv.z, fv.w);
      *(short4*)((char*)Xraw + c * 256 + ((2 * tq) ^ ((c & 7) << 4))) = pk.s4;
    }
  }
  __syncthreads();

  short* xb = Xb + (size_t)((b * 64 + f) * 16) * 4096;
  #pragma unroll
  for (int it = 0; it < 8; ++it) {
    const int chunk = tid + it * 256;
    const int c8 = chunk >> 7, tl = chunk & 127;
    sh8 o;
    #pragma unroll
    for (int e = 0; e < 8; ++e)
      o[e] = *((const short*)((const char*)Xraw + (c8 * 8 + e) * 256 + ((2 * tl) ^ (e << 4))));
    *(sh8*)(xb + ((size_t)c8 * 512 + tt * 128 + tl) * 8) = o;
  }
}

// ---------------------------------------------------------------------------
// kA: per (b, f, tt): Y[384,128] = W @ X; bias+PReLU; stats; stores
//   Q~/K~ packed planes Qp4/Kp4 [bh][dq=d'/4][t]{4 shorts} (128B runs),
//   V raw [bh][d][t] via LDS restage (16B coalesced stores).
__global__ __launch_bounds__(512) void kA_qkv(
    const short* __restrict__ Xb, const short* __restrict__ wb,
    const float* __restrict__ bias, const float* __restrict__ alphap,
    const float* __restrict__ gq, const float* __restrict__ bq,
    short* __restrict__ Qp4, short* __restrict__ Kp4, short* __restrict__ Vt,
    float* __restrict__ Pstat)
{
  const int bid = blockIdx.x;
  const int b = bid >> 8, f = (bid >> 2) & 63, tt = bid & 3;
  const int tid = threadIdx.x, lane = tid & 63, w = tid >> 6;

  __shared__ float psum[8 * 8 * 16 * 6];   // [w][ni][l16][ch], 24KB
  __shared__ char vls[32768];              // V restage [128 row][128 t] bf16 swz

  fx4 acc[3][8];
  #pragma unroll
  for (int mi = 0; mi < 3; ++mi)
    #pragma unroll
    for (int ni = 0; ni < 8; ++ni) acc[mi][ni] = fx4{0.f, 0.f, 0.f, 0.f};

  const short* xb = Xb + (size_t)((b * 64 + f) * 16) * 4096;

  #pragma unroll
  for (int ks = 0; ks < 4; ++ks) {
    sh8 a[3];
    #pragma unroll
    for (int mi = 0; mi < 3; ++mi) {
      const int o = w * 48 + mi * 16 + (lane & 15);
      a[mi] = *(const sh8*)(wb + o * 128 + ks * 32 + (lane >> 4) * 8);
    }
    #pragma unroll
    for (int ni = 0; ni < 8; ++ni) {
      const sh8 bf = *(const sh8*)(xb + ((size_t)(ks * 4 + (lane >> 4)) * 512 +
                                         tt * 128 + ni * 16 + (lane & 15)) * 8);
      #pragma unroll
      for (int mi = 0; mi < 3; ++mi)
        acc[mi][ni] = mfma_bf16(a[mi], bf, acc[mi][ni]);
    }
  }

  float gqq[4], gqk[4], bqq[4], bqk[4];
  #pragma unroll
  for (int r = 0; r < 4; ++r) {
    const int dp = f * 16 + (lane >> 4) * 4 + r;
    gqq[r] = gq[w * 1024 + dp];
    gqk[r] = gq[(8 + w) * 1024 + dp];
    bqq[r] = bq[w * 1024 + dp];
    bqk[r] = bq[(8 + w) * 1024 + dp];
  }

  const float alpha = alphap[0];
  #pragma unroll
  for (int ni = 0; ni < 8; ++ni) {
    float t0 = 0.f, t1 = 0.f, taq = 0.f, tuq = 0.f, tak = 0.f, tuk = 0.f;
    #pragma unroll
    for (int mi = 0; mi < 3; ++mi)
      #pragma unroll
      for (int r = 0; r < 4; ++r) {
        const int o = w * 48 + mi * 16 + (lane >> 4) * 4 + r;
        float v = acc[mi][ni][r] + bias[o];
        v = (v >= 0.f) ? v : alpha * v;
        acc[mi][ni][r] = v;
        t0 += v; t1 += v * v;
        if (mi == 0) { const float qt = v * gqq[r]; taq += qt * gqk[r]; tuq += qt * bqk[r]; }
        if (mi == 1) { const float kt = v * gqk[r]; tak += kt * gqq[r]; tuk += kt * bqq[r]; }
      }
    t0 += __shfl_down(t0, 32); t1 += __shfl_down(t1, 32);
    taq += __shfl_down(taq, 32); tuq += __shfl_down(tuq, 32);
    tak += __shfl_down(tak, 32); tuk += __shfl_down(tuk, 32);
    t0 += __shfl_down(t0, 16); t1 += __shfl_down(t1, 16);
    taq += __shfl_down(taq, 16); tuq += __shfl_down(tuq, 16);
    tak += __shfl_down(tak, 16); tuk += __shfl_down(tuk, 16);
    if (lane < 16) {
      float* ps = &psum[((w * 8 + ni) * 16 + lane) * 6];
      ps[0] = t0; ps[1] = t1; ps[2] = taq; ps[3] = tuq; ps[4] = tak; ps[5] = tuk;
    }
  }

  // V -> LDS restage (post-PReLU values), swizzled rows of 128 t
  #pragma unroll
  for (int ni = 0; ni < 8; ++ni)
    #pragma unroll
    for (int r = 0; r < 4; ++r) {
      const int row = w * 16 + (lane >> 4) * 4 + r;
      const int tl = ni * 16 + (lane & 15);
      *((short*)(vls + row * 256 + ((tl * 2) ^ ((row & 7) << 4)))) =
          (short)(pk_bf16(acc[2][ni][r], acc[2][ni][r]) & 0xffffu);
    }
  __syncthreads();

  if (tid < 256) {
    const int col = tid & 127, s = tid >> 7;
    const int ni = col >> 4, l = col & 15;
    float a0 = 0.f;
    #pragma unroll
    for (int ww = 0; ww < 8; ++ww) a0 += psum[((ww * 8 + ni) * 16 + l) * 6 + s];
    Pstat[(size_t)s * 131072 + (size_t)b * 32768 + (size_t)f * 512 + tt * 128 + col] = a0;
  }
  #pragma unroll
  for (int p = 0; p < 8; ++p) {
    const int idx = p * 512 + tid;
    const int col = idx & 127, wc = idx >> 7;
    const int ww = wc >> 2, ch = wc & 3;
    const int ni = col >> 4, l = col & 15;
    Pstat[(size_t)(2 + ww * 4 + ch) * 131072 + (size_t)b * 32768 +
          (size_t)f * 512 + tt * 128 + col] = psum[((ww * 8 + ni) * 16 + l) * 6 + 2 + ch];
  }

  // stores: Qp4/Kp4 packed planes (128B runs per 16 lanes)
  const int bh = b * 8 + w;
  const int dq = f * 4 + (lane >> 4);
  #pragma unroll
  for (int mi = 0; mi < 2; ++mi) {
    short* dstp = (mi ? Kp4 : Qp4) + ((size_t)(bh * 256 + dq) * 512 + tt * 128) * 4;
    #pragma unroll
    for (int ni = 0; ni < 8; ++ni) {
      const int tl = ni * 16 + (lane & 15);
      float v0 = acc[mi][ni][0] * (mi == 0 ? gqq[0] : gqk[0]);
      float v1 = acc[mi][ni][1] * (mi == 0 ? gqq[1] : gqk[1]);
      float v2 = acc[mi][ni][2] * (mi == 0 ? gqq[2] : gqk[2]);
      float v3 = acc[mi][ni][3] * (mi == 0 ? gqq[3] : gqk[3]);
      uint2 pk;
      pk.x = pk_bf16(v0, v1);
      pk.y = pk_bf16(v2, v3);
      *(uint2*)(dstp + tl * 4) = pk;
    }
  }
  // V: vector stores from LDS (256B runs per 16 lanes)
  #pragma unroll
  for (int it = 0; it < 4; ++it) {
    const int c = it * 512 + tid;
    const int row = c >> 4, seg = c & 15;
    const sh8 vv = *(const sh8*)(vls + row * 256 + ((seg * 16) ^ ((row & 7) << 4)));
    const int bh2 = b * 8 + (row >> 4);
    const int d2 = (row & 15) * 64 + f;
    *(sh8*)(Vt + ((size_t)bh2 * 1024 + d2) * 512 + tt * 128 + seg * 8) = vv;
  }
}

// ---------------------------------------------------------------------------
// k_stats: RowB[bh][t][8] = {rs, rm, rs*aq, rs*uq - rm*Gqb, rs*ak, rs*uk - rm*Gkb, 0, 0}
__global__ __launch_bounds__(256) void k_stats(const float* __restrict__ Pstat,
                                               const float* __restrict__ HC,
                                               float* __restrict__ RowB)
{
  const int idx = blockIdx.x * 256 + threadIdx.x;   // 16384
  const int b = idx >> 12, h = (idx >> 9) & 7, t = idx & 511;
  const float* P0 = Pstat + (size_t)b * 32768 + t;
  float s0 = 0.f, s1 = 0.f, aq = 0.f, uq = 0.f, ak = 0.f, uk = 0.f;
  for (int fq = 0; fq < 64; ++fq) {
    const size_t o = (size_t)fq * 512;
    s0 += P0[o];
    s1 += P0[(size_t)131072 + o];
    aq += P0[(size_t)(2 + h * 4 + 0) * 131072 + o];
    uq += P0[(size_t)(2 + h * 4 + 1) * 131072 + o];
    ak += P0[(size_t)(2 + h * 4 + 2) * 131072 + o];
    uk += P0[(size_t)(2 + h * 4 + 3) * 131072 + o];
  }
  const float mu = s0 * (1.f / 24576.f);
  const float var = s1 * (1.f / 24576.f) - mu * mu;
  const float rs = rsqrtf(var + 1e-5f);
  const float rm = rs * mu;
  float* o8 = RowB + ((size_t)(b * 8 + h) * 512 + t) * 8;
  o8[0] = rs;
  o8[1] = rm;
  o8[2] = rs * aq;
  o8[3] = rs * uq - rm * HC[h * 4 + 1];
  o8[4] = rs * ak;
  o8[5] = rs * uk - rm * HC[h * 4 + 2];
  o8[6] = 0.f; o8[7] = 0.f;
}

// ---------------------------------------------------------------------------
// k_qk: S = affine-corrected (Q~.K~)/32, lower-tri 128x128 tiles. Fragments
//   loaded DIRECTLY from packed global planes (L2-hot); no LDS staging.
__global__ __launch_bounds__(256) void k_qk(
    const short* __restrict__ Qp4, const short* __restrict__ Kp4,
    const float* __restrict__ RowB, const float* __restrict__ HC,
    float* __restrict__ S)
{
  const int bid = blockIdx.x;
  const int bh = bid / 10;
  const int j = bid - bh * 10;
  const int qi = (j >= 6) ? 3 : (j >= 3) ? 2 : (j >= 1) ? 1 : 0;
  const int ki = j - qi * (qi + 1) / 2;
  const int b = bh >> 3, h = bh & 7;
  const int tid = threadIdx.x, lane = tid & 63, w = tid >> 6;
  const int wm = w >> 1, wn = w & 1;

  __shared__ float4 qb[128];   // {rs, rm, Aq, Uq}
  __shared__ float4 kb[128];   // {rs, rm, Ak, Uk}

  if (tid < 128) {
    const float* rb = RowB + ((size_t)(b * 8 + h) * 512 + qi * 128 + tid) * 8;
    qb[tid] = float4{rb[0], rb[1], rb[2], rb[3]};
  } else {
    const float* rb = RowB + ((size_t)(b * 8 + h) * 512 + ki * 128 + (tid - 128)) * 8;
    kb[tid - 128] = float4{rb[0], rb[1], rb[4], rb[5]};
  }
  __syncthreads();

  const float Ggg = HC[h * 4 + 0], Bbb = HC[h * 4 + 3];

  const short* Qbase = Qp4 + (size_t)bh * 256 * 512 * 4;
  const short* Kbase = Kp4 + (size_t)bh * 256 * 512 * 4;
  const short* pA[4];
  const short* pB[4];
  #pragma unroll
  for (int mi = 0; mi < 4; ++mi) {
    const int t = qi * 128 + wm * 64 + mi * 16 + (lane & 15);
    pA[mi] = Qbase + ((size_t)((lane >> 4) * 2) * 512 + t) * 4;
    const int t2 = ki * 128 + wn * 64 + mi * 16 + (lane & 15);
    pB[mi] = Kbase + ((size_t)((lane >> 4) * 2) * 512 + t2) * 4;
  }

  fx4 acc[4][4];
  #pragma unroll
  for (int mi = 0; mi < 4; ++mi)
    #pragma unroll
    for (int ni = 0; ni < 4; ++ni) acc[mi][ni] = fx4{0.f, 0.f, 0.f, 0.f};

  for (int kc = 0; kc < 32; ++kc) {   // 32 d' per step; dq stride 8 planes
    const size_t off = (size_t)kc * 8 * 512 * 4;   // shorts
    sh8 a[4], bb[4];
    #pragma unroll
    for (int mi = 0; mi < 4; ++mi) {
      const uint2 x0 = *(const uint2*)(pA[mi] + off);
      const uint2 x1 = *(const uint2*)(pA[mi] + off + 2048);
      union { unsigned u[4]; sh8 s; } c; c.u[0] = x0.x; c.u[1] = x0.y; c.u[2] = x1.x; c.u[3] = x1.y;
      a[mi] = c.s;
    }
    #pragma unroll
    for (int ni = 0; ni < 4; ++ni) {
      const uint2 x0 = *(const uint2*)(pB[ni] + off);
      const uint2 x1 = *(const uint2*)(pB[ni] + off + 2048);
      union { unsigned u[4]; sh8 s; } c; c.u[0] = x0.x; c.u[1] = x0.y; c.u[2] = x1.x; c.u[3] = x1.y;
      bb[ni] = c.s;
    }
    #pragma unroll
    for (int mi = 0; mi < 4; ++mi)
      #pragma unroll
      for (int ni = 0; ni < 4; ++ni)
        acc[mi][ni] = mfma_bf16(a[mi], bb[ni], acc[mi][ni]);
  }

  float* Sg = S + (size_t)bh * 262144;
  const int q0 = qi * 128 + wm * 64, k0 = ki * 128 + wn * 64;
  #pragma unroll
  for (int mi = 0; mi < 4; ++mi)
    #pragma unroll
    for (int ni = 0; ni < 4; ++ni) {
      const int kl = wn * 64 + ni * 16 + (lane & 15);
      const float4 kv = kb[kl];
      const int kc2 = k0 + ni * 16 + (lane & 15);
      #pragma unroll
      for (int r = 0; r < 4; ++r) {
        const int qll = wm * 64 + mi * 16 + (lane >> 4) * 4 + r;
        const float4 qv = qb[qll];
        float s = acc[mi][ni][r];
        s = qv.x * kv.x * s - qv.z * kv.y - qv.y * kv.z + (qv.y * kv.y) * Ggg
            + qv.w + kv.w + Bbb;
        Sg[(size_t)(q0 + mi * 16 + (lane >> 4) * 4 + r) * 512 + kc2] = s * 0.03125f;
      }
    }
}

// ---------------------------------------------------------------------------
// k_softmax: causal softmax; emits P'' = p * rs_k / L (bf16, zeros above diag)
//   and saq' = sum(p * rm_k)/L into RowB[..][6].
__global__ __launch_bounds__(256) void k_softmax(const float* __restrict__ S,
                                                 short* __restrict__ Pb,
                                                 float* __restrict__ RowB)
{
  const int row = blockIdx.x * 4 + (threadIdx.x >> 6);
  const int lane = threadIdx.x & 63;
  const int bh = row >> 9, q = row & 511;
  const float* Sr = S + (size_t)bh * 262144 + (size_t)q * 512;
  short* Pr = Pb + (size_t)bh * 262144 + (size_t)q * 512;
  const float* rbk = RowB + (size_t)bh * 512 * 8;
  const int n = q + 1;
  float v[8], rsx[8], rmx[8];
  float mx = -1e30f;
  #pragma unroll
  for (int i = 0; i < 8; ++i) {
    const int k = lane + i * 64;
    v[i] = (k < n) ? Sr[k] : -1e30f;
    mx = fmaxf(mx, v[i]);
    const float2 rr = *(const float2*)(rbk + (size_t)k * 8);
    rsx[i] = rr.x; rmx[i] = rr.y;
  }
  #pragma unroll
  for (int off = 32; off > 0; off >>= 1) mx = fmaxf(mx, __shfl_xor(mx, off));
  float sum = 0.f, saq = 0.f;
  #pragma unroll
  for (int i = 0; i < 8; ++i) {
    const float e = (v[i] > -1e29f) ? __expf(v[i] - mx) : 0.f;
    v[i] = e; sum += e; saq += e * rmx[i];
  }
  #pragma unroll
  for (int off = 32; off > 0; off >>= 1) {
    sum += __shfl_xor(sum, off); saq += __shfl_xor(saq, off);
  }
  const float inv = 1.f / sum;
  #pragma unroll
  for (int i = 0; i < 8; ++i) Pr[lane + i * 64] = bf16r(v[i] * rsx[i] * inv);
  if (lane == 0) RowB[((size_t)bh * 512 + q) * 8 + 6] = saq * inv;
}

// ---------------------------------------------------------------------------
// k_pv: ctx = P'' @ V(raw), BK=64; epilogue gv*(acc - saq') + bv; -> Cs.
__global__ __launch_bounds__(256) void k_pv(
    const short* __restrict__ Pb, const short* __restrict__ Vt,
    const float* __restrict__ RowB, const float* __restrict__ gvt,
    const float* __restrict__ bvt, short* __restrict__ Cs)
{
  const int bid = blockIdx.x;
  const int bh = bid >> 5, qi = (bid >> 3) & 3, dt = bid & 7;
  const int b = bh >> 3, h = bh & 7;
  const int tid = threadIdx.x, lane = tid & 63, w = tid >> 6;
  const int wm = w >> 1, wn = w & 1;

  __shared__ char smem[32768];
  short* Ps = (short*)smem;                // [128 q][64 k], 128B pitch
  short* Vs = (short*)(smem + 16384);      // [128 d][64 k]
  short* ctile = (short*)smem;             // [128 d][128 q] reuse after loop
  __shared__ float saqv[128];

  const short* Pg = Pb + ((size_t)bh * 512 + qi * 128) * 512;
  const short* Vg = Vt + ((size_t)bh * 1024 + dt * 128) * 512;

  if (tid < 128)
    saqv[tid] = RowB[((size_t)bh * 512 + qi * 128 + tid) * 8 + 6];

  const int rowslot = tid >> 3, unit = tid & 7;

  fx4 acc[4][4];
  #pragma unroll
  for (int mi = 0; mi < 4; ++mi)
    #pragma unroll
    for (int ni = 0; ni < 4; ++ni) acc[mi][ni] = fx4{0.f, 0.f, 0.f, 0.f};

  const int nks = (qi + 1) * 2;
  for (int ks = 0; ks < nks; ++ks) {
    __syncthreads();
    #pragma unroll
    for (int rit = 0; rit < 4; ++rit) {
      const int rr2 = rit * 32 + rowslot;
      const sh8 p = *(const sh8*)(Pg + (size_t)rr2 * 512 + ks * 64 + unit * 8);
      *(sh8*)((char*)Ps + rr2 * 128 + ((unit * 16) ^ ((rr2 & 7) << 4))) = p;
      const sh8 vv = *(const sh8*)(Vg + (size_t)rr2 * 512 + ks * 64 + unit * 8);
      *(sh8*)((char*)Vs + rr2 * 128 + ((unit * 16) ^ ((rr2 & 7) << 4))) = vv;
    }
    __syncthreads();
    #pragma unroll
    for (int ksub = 0; ksub < 2; ++ksub) {
      sh8 a[4], bb[4];
      #pragma unroll
      for (int mi = 0; mi < 4; ++mi) {
        const int r2 = wm * 64 + mi * 16 + (lane & 15);
        a[mi] = *(const sh8*)((const char*)Ps + r2 * 128 +
                ((ksub * 64 + (lane >> 4) * 16) ^ ((r2 & 7) << 4)));
      }
      #pragma unroll
      for (int ni = 0; ni < 4; ++ni) {
        const int r2 = wn * 64 + ni * 16 + (lane & 15);
        bb[ni] = *(const sh8*)((const char*)Vs + r2 * 128 +
                 ((ksub * 64 + (lane >> 4) * 16) ^ ((r2 & 7) << 4)));
      }
      #pragma unroll
      for (int mi = 0; mi < 4; ++mi)
        #pragma unroll
        for (int ni = 0; ni < 4; ++ni)
          acc[mi][ni] = mfma_bf16(a[mi], bb[ni], acc[mi][ni]);
    }
  }
  __syncthreads();   // protect Ps/Vs reads before ctile overwrite

  #pragma unroll
  for (int mi = 0; mi < 4; ++mi)
    #pragma unroll
    for (int ni = 0; ni < 4; ++ni) {
      const int ql = wm * 64 + mi * 16 + (lane >> 4) * 4;
      const int dl = wn * 64 + ni * 16 + (lane & 15);
      const float gvv = gvt[h * 1024 + dt * 128 + dl];
      const float bvv = bvt[h * 1024 + dt * 128 + dl];
      const int swz = (dl & 7) << 4;
      #pragma unroll
      for (int r = 0; r < 4; ++r) {
        const float o = gvv * (acc[mi][ni][r] - saqv[ql + r]) + bvv;
        ctile[(dl * 256 + ((2 * (ql + r)) ^ swz)) >> 1] = bf16r(o);
      }
    }
  __syncthreads();

  // scrambled write: c[b][C][t2][f2] in 128B f2-runs
  const int cl_loc = tid >> 7, fq = (tid >> 1) & 63, tg_loc = tid & 1;
  const int C = h * 16 + dt * 2 + cl_loc;
  const int t2 = fq * 8 + qi * 2 + tg_loc;
  const int dl = cl_loc * 64 + fq;
  const int swz = (dl & 7) << 4;
  short* dst = Cs + (((size_t)b * 128 + C) * 512 + t2) * 64;
  #pragma unroll
  for (int jj = 0; jj < 8; ++jj) {
    const sh8 vv = *(const sh8*)((const char*)ctile + dl * 256 + ((tg_loc * 128 + jj * 16) ^ swz));
    *(sh8*)(dst + jj * 8) = vv;
  }
}

// ---------------------------------------------------------------------------
// k_proj: per (b,t2): Y[128,64] = Wp @ C; bias+PReLU+LN; -> Otmp bf16 [b][o][t2][f2]
__global__ __launch_bounds__(512) void k_proj(
    const short* __restrict__ Cs, const short* __restrict__ wb,
    const float* __restrict__ bias, const float* __restrict__ alphap,
    const float* __restrict__ gamma, const float* __restrict__ beta,
    short* __restrict__ Otmpb)
{
  const int bid = blockIdx.x;
  const int b = bid >> 9, t2 = bid & 511;
  const int tid = threadIdx.x, lane = tid & 63, w = tid >> 6;

  __shared__ short Xs[64 * 128];
  __shared__ float red[18];

  {
    const int rowslot = tid >> 3, unit = tid & 7;
    #pragma unroll
    for (int rit = 0; rit < 2; ++rit) {
      const int C = rit * 64 + rowslot;
      const sh8 vv = *(const sh8*)(Cs + (((size_t)b * 128 + C) * 512 + t2) * 64 + unit * 8);
      #pragma unroll
      for (int jj = 0; jj < 8; ++jj) {
        const int f2 = unit * 8 + jj;
        *((short*)((char*)Xs + f2 * 256 + ((2 * C) ^ ((f2 & 7) << 4)))) = vv[jj];
      }
    }
  }
  __syncthreads();

  const float alpha = alphap[0];
  fx4 acc[4];
  #pragma unroll
  for (int ni = 0; ni < 4; ++ni) acc[ni] = fx4{0.f, 0.f, 0.f, 0.f};

  #pragma unroll
  for (int ks = 0; ks < 4; ++ks) {
    const int o = w * 16 + (lane & 15);
    const sh8 a = *(const sh8*)(wb + o * 128 + ks * 32 + (lane >> 4) * 8);
    #pragma unroll
    for (int ni = 0; ni < 4; ++ni) {
      const int f2 = ni * 16 + (lane & 15);
      const sh8 bf = *(const sh8*)((const char*)Xs + f2 * 256 +
                     ((ks * 64 + (lane >> 4) * 16) ^ ((f2 & 7) << 4)));
      acc[ni] = mfma_bf16(a, bf, acc[ni]);
    }
  }

  float s0 = 0.f, s1 = 0.f;
  const int ob = w * 16 + (lane >> 4) * 4;
  #pragma unroll
  for (int ni = 0; ni < 4; ++ni)
    #pragma unroll
    for (int r = 0; r < 4; ++r) {
      float v = acc[ni][r] + bias[ob + r];
      v = (v >= 0.f) ? v : alpha * v;
      acc[ni][r] = v;
      s0 += v; s1 += v * v;
    }
  #pragma unroll
  for (int off = 32; off > 0; off >>= 1) { s0 += __shfl_down(s0, off); s1 += __shfl_down(s1, off); }
  if (lane == 0) { red[w * 2] = s0; red[w * 2 + 1] = s1; }
  __syncthreads();
  if (tid == 0) {
    float a0 = 0.f, a1 = 0.f;
    for (int i2 = 0; i2 < 8; ++i2) { a0 += red[2 * i2]; a1 += red[2 * i2 + 1]; }
    const float mu = a0 / 8192.f;
    const float var = a1 / 8192.f - mu * mu;
    red[16] = mu; red[17] = rsqrtf(var + 1e-5f);
  }
  __syncthreads();
  const float mu = red[16], rstd = red[17];

  #pragma unroll
  for (int ni = 0; ni < 4; ++ni) {
    const int f2 = ni * 16 + (lane & 15);
    #pragma unroll
    for (int r = 0; r < 4; ++r) {
      const int o = ob + r;
      const float zz = (acc[ni][r] - mu) * rstd * gamma[o * 64 + f2] + beta[o * 64 + f2];
      Otmpb[(((size_t)b * 128 + o) * 512 + t2) * 64 + f2] = bf16r(zz);
    }
  }
}

// ---------------------------------------------------------------------------
// k_trans: Otmp bf16 [b][o][t2][f2] -> out f32 [b][o][f2][t2]
__global__ __launch_bounds__(256) void k_trans(const short* __restrict__ Otmpb,
                                               float* __restrict__ out)
{
  const int bid = blockIdx.x;
  const int bo = bid >> 3, tt8 = bid & 7;
  const int t20 = tt8 * 64;
  const int tid = threadIdx.x;
  __shared__ float Ltr[64 * 68];

  {
    const int t2l = tid >> 2, u = tid & 3;
    const short* srow = Otmpb + ((size_t)bo * 512 + t20 + t2l) * 64 + u * 16;
    const sh8 v0 = *(const sh8*)(srow);
    const sh8 v1 = *(const sh8*)(srow + 8);
    #pragma unroll
    for (int e = 0; e < 8; ++e) {
      Ltr[(u * 16 + e) * 68 + t2l]     = b2f(v0[e]);
      Ltr[(u * 16 + 8 + e) * 68 + t2l] = b2f(v1[e]);
    }
  }
  __syncthreads();
  {
    const int f2 = tid >> 2, u = tid & 3;
    float* dst = out + ((size_t)bo * 64 + f2) * 512 + t20 + u * 16;
    #pragma unroll
    for (int k = 0; k < 4; ++k)
      *(float4*)(dst + k * 4) = *(const float4*)&Ltr[f2 * 68 + u * 16 + k * 4];
  }
}

// ---------------------------------------------------------------------------
extern "C" void kernel_launch(void* const* d_in, const int* in_sizes, int n_in,
                              void* d_out, int out_size, void* d_ws, size_t ws_size,
                              hipStream_t stream) {
  (void)in_sizes; (void)n_in; (void)out_size;
  const float* x          = (const float*)d_in[0];
  const float* qkv_w      = (const float*)d_in[1];
  const float* qkv_b      = (const float*)d_in[2];
  const float* qkv_alpha  = (const float*)d_in[3];
  const float* qkv_gamma  = (const float*)d_in[4];
  const float* qkv_beta   = (const float*)d_in[5];
  const float* proj_w     = (const float*)d_in[6];
  const float* proj_b     = (const float*)d_in[7];
  const float* proj_alpha = (const float*)d_in[8];
  const float* proj_gamma = (const float*)d_in[9];
  const float* proj_beta  = (const float*)d_in[10];
  float* out = (float*)d_out;

  // ws layout (total 167,903,232 B known safe); all regions disjoint per lifetime:
  //  @0        Qp4 (33.5M) [kA -> k_qk]   ; Cs (33.5M) [k_pv -> k_proj]
  //  @33.5M    Kp4 (33.5M) [kA -> k_qk]   ; Otmpb (33.5M) [k_proj -> k_trans]
  //  @67M      Vt  (33.5M) [kA -> k_pv]
  //  @100.7M   Xb  (33.5M) [k_xt -> kA]   ; S f32 (33.5M) [k_qk -> k_softmax]
  //  @134.2M   Pb  (16.8M) [k_softmax -> k_pv]
  //  @150.99M  RowB (512K); gq/bq (64K ea); gv/bv (32K ea); HC
  //  @167.77M  qwb (96K), pwb (32K)
  //  Pstat (17.8M) in d_out, fully overwritten by k_trans.
  char* ws = (char*)d_ws;
  short* Qp4  = (short*)(ws + 0);
  short* Cs   = (short*)(ws + 0);
  short* Kp4  = (short*)(ws + 33554432);
  short* Otmpb= (short*)(ws + 33554432);
  short* Vt   = (short*)(ws + 67108864);
  short* Xb   = (short*)(ws + 100663296);
  float* S    = (float*)(ws + 100663296);
  short* Pb   = (short*)(ws + 134217728);
  float* RowB = (float*)(ws + 150994944);
  float* gq   = (float*)(ws + 151519232);
  float* bq   = (float*)(ws + 151584768);
  float* gv   = (float*)(ws + 151650304);
  float* bv   = (float*)(ws + 151683072);
  float* HC   = (float*)(ws + 151715840);
  short* qwb  = (short*)(ws + 167772160);
  short* pwb  = (short*)(ws + 167870464);
  float* Pstat = (float*)d_out;
  if (ws_size < 167903232u) return;

  k_prep<<<200, 256, 0, stream>>>(qkv_w, proj_w, qkv_gamma, qkv_beta,
                                  qwb, pwb, gq, bq, gv, bv, HC);
  k_xt<<<1024, 256, 0, stream>>>(x, Xb);
  kA_qkv<<<1024, 512, 0, stream>>>(Xb, qwb, qkv_b, qkv_alpha, gq, bq,
                                   Qp4, Kp4, Vt, Pstat);
  k_stats<<<64, 256, 0, stream>>>(Pstat, HC, RowB);
  k_qk<<<320, 256, 0, stream>>>(Qp4, Kp4, RowB, HC, S);
  k_softmax<<<4096, 256, 0, stream>>>(S, Pb, RowB);
  k_pv<<<1024, 256, 0, stream>>>(Pb, Vt, RowB, gv, bv, Cs);
  k_proj<<<2048, 512, 0, stream>>>(Cs, pwb, proj_b, proj_alpha, proj_gamma, proj_beta, Otmpb);
  k_trans<<<4096, 256, 0, stream>>>(Otmpb, out);
}